// Round 4
// baseline (541.406 us; speedup 1.0000x reference)
//
#include <hip/hip_runtime.h>
#include <stdint.h>

// ---- Problem constants ----
#define NDRUGS 10000
#define NTAILS 20000
#define NE     1000000
#define SSIZE  16

typedef unsigned int  u32;
typedef unsigned short u16;
typedef unsigned long long u64;

// ---- Threefry-2x32-20 (exact JAX semantics) ----
__host__ __device__ __forceinline__ void tf2x32(u32 k0, u32 k1, u32 x0, u32 x1,
                                                u32& o0, u32& o1) {
  u32 ks2 = k0 ^ k1 ^ 0x1BD11BDAu;
  x0 += k0; x1 += k1;
#define TFR(r) { x0 += x1; x1 = (x1 << r) | (x1 >> (32 - r)); x1 ^= x0; }
  TFR(13) TFR(15) TFR(26) TFR(6)
  x0 += k1; x1 += ks2 + 1u;
  TFR(17) TFR(29) TFR(16) TFR(24)
  x0 += ks2; x1 += k0 + 2u;
  TFR(13) TFR(15) TFR(26) TFR(6)
  x0 += k0; x1 += k1 + 3u;
  TFR(17) TFR(29) TFR(16) TFR(24)
  x0 += k1; x1 += ks2 + 4u;
  TFR(13) TFR(15) TFR(26) TFR(6)
  x0 += ks2; x1 += k0 + 5u;
#undef TFR
  o0 = x0; o1 = x1;
}

// 32-bit random_bits under partitionable semantics: fold of the two words
__device__ __forceinline__ u32 rbits32(u32 kx, u32 ky, u32 i) {
  u32 o0, o1;
  tf2x32(kx, ky, 0u, i, o0, o1);
  return o0 ^ o1;
}

// ---- bf16 helpers (RNE, matches numpy/jax .astype(bfloat16)) ----
__device__ __forceinline__ float bf2f(u16 u) {
  u32 x = ((u32)u) << 16;
  return __builtin_bit_cast(float, x);
}
__device__ __forceinline__ u16 f2bf(float f) {
  u32 x = __builtin_bit_cast(u32, f);
  u32 lsb = (x >> 16) & 1u;
  x += 0x7fffu + lsb;
  return (u16)(x >> 16);
}
// f32 -> nearest-bf16 value, kept in f32 (emulates the harness's bf16 cast of inputs)
__device__ __forceinline__ float q16(float f) { return bf2f(f2bf(f)); }

// Dual-dtype quantized load. Probe gamma (= ones): dword0 0x3F800000 -> f32
// inputs (cast to bf16 values to match np ref); 0x3F803F80 -> bf16 inputs.
#define F32MAGIC 0x3F800000u
__device__ __forceinline__ float ldx(const void* p, int idx, bool f32in) {
  return f32in ? q16(((const float*)p)[idx]) : bf2f(((const u16*)p)[idx]);
}

// ---- Phase 1: degree histogram (dtype-independent) ----
__global__ __launch_bounds__(256) void k_hist(const int* __restrict__ dkg,
                                              int* __restrict__ deg) {
  int i = blockIdx.x * 256 + threadIdx.x;
  if (i >= NE) return;
  atomicAdd(&deg[dkg[3 * i]], 1);
}

// ---- Phase 2: exclusive scan of degrees (single block) ----
__global__ __launch_bounds__(1024) void k_scan(const int* __restrict__ deg,
                                               int* __restrict__ offsets) {
  __shared__ int part[1024];
  int t = threadIdx.x;
  const int chunk = 10;  // 1024*10 >= NDRUGS
  int base = t * chunk;
  int s = 0;
  for (int i = 0; i < chunk; i++) {
    int idx = base + i;
    if (idx < NDRUGS) s += deg[idx];
  }
  part[t] = s;
  __syncthreads();
  for (int off = 1; off < 1024; off <<= 1) {
    int v = (t >= off) ? part[t - off] : 0;
    __syncthreads();
    part[t] += v;
    __syncthreads();
  }
  int run = (t == 0) ? 0 : part[t - 1];
  for (int i = 0; i < chunk; i++) {
    int idx = base + i;
    if (idx < NDRUGS) { offsets[idx] = run; run += deg[idx]; }
  }
}

// ---- Phase 3: bucket edges by head (counting sort, arbitrary intra-order) ----
__global__ __launch_bounds__(256) void k_scatter(const int* __restrict__ dkg,
                                                 const int* __restrict__ offsets,
                                                 int* __restrict__ cursor,
                                                 int* __restrict__ bucket) {
  int i = blockIdx.x * 256 + threadIdx.x;
  if (i >= NE) return;
  int h = dkg[3 * i];
  int pos = offsets[h] + atomicAdd(&cursor[h], 1);
  bucket[pos] = i;
}

// ---- Phase 4: per-drug selection of the 16 sampled edges ----
// Composite key ((r_bits>>9)<<32)|edge_idx reproduces the stable lexsort order
// exactly (uniform float order == order of bits>>9; ties broken by index).
// deg>=16: 16 smallest keys. deg<16: all (sorted) + (16-deg) draws at rank u%deg.
__global__ __launch_bounds__(64) void k_select(const int* __restrict__ bucket,
                                               const int* __restrict__ deg,
                                               const int* __restrict__ offsets,
                                               int* __restrict__ sel,
                                               u32 k1x, u32 k1y,
                                               u32 khx, u32 khy,
                                               u32 klx, u32 kly) {
  __shared__ u64 hp[SSIZE * 64];
  int t = threadIdx.x;
  int d = blockIdx.x * 64 + t;
  if (d >= NDRUGS) return;   // no barriers below
  int dg = deg[d], off = offsets[d];
  if (dg <= 0) {
    for (int s = 0; s < SSIZE; s++) sel[d * SSIZE + s] = -1;
    return;
  }
  if (dg >= SSIZE) {
    u64 mx = 0; int mi = 0;
    for (int s = 0; s < SSIZE; s++) {
      int e = bucket[off + s];
      u64 k = ((u64)(rbits32(k1x, k1y, (u32)e) >> 9) << 32) | (u32)e;
      hp[s * 64 + t] = k;
      if (k > mx) { mx = k; mi = s; }
    }
    for (int p = SSIZE; p < dg; p++) {
      int e = bucket[off + p];
      u64 k = ((u64)(rbits32(k1x, k1y, (u32)e) >> 9) << 32) | (u32)e;
      if (k < mx) {
        hp[mi * 64 + t] = k;
        mx = 0;
        for (int s = 0; s < SSIZE; s++) {
          u64 v = hp[s * 64 + t];
          if (v > mx) { mx = v; mi = s; }
        }
      }
    }
    for (int s = 0; s < SSIZE; s++)
      sel[d * SSIZE + s] = (int)(hp[s * 64 + t] & 0xffffffffu);
  } else {
    u64 a[SSIZE];
    for (int i = 0; i < dg; i++) {
      int e = bucket[off + i];
      a[i] = ((u64)(rbits32(k1x, k1y, (u32)e) >> 9) << 32) | (u32)e;
    }
    for (int i = 1; i < dg; i++) {  // insertion sort ascending
      u64 v = a[i]; int jj = i - 1;
      while (jj >= 0 && a[jj] > v) { a[jj + 1] = a[jj]; jj--; }
      a[jj + 1] = v;
    }
    for (int i = 0; i < dg; i++) sel[d * SSIZE + i] = (int)(a[i] & 0xffffffffu);
    int need = SSIZE - dg;
    const u32 span = 0x7fffffffu;  // 2^31-1; multiplier = 2^32 % span = 2
    for (int s = 0; s < need; s++) {
      u32 j = (u32)(d * SSIZE + s);
      u32 hi = rbits32(khx, khy, j) % span;
      u32 lo = rbits32(klx, kly, j) % span;
      u32 u = (hi * 2u + lo) % span;     // uint32 wraparound then mod: JAX-exact
      int idx = (int)(u % (u32)dg);
      sel[d * SSIZE + dg + s] = (int)(a[idx] & 0xffffffffu);
    }
  }
}

// ---- Phase 5 (fused): per-drug edge-MLP score + neighbor gather + concat GEMM ----
// score(e) = sigmoid(v@W1+b1) . rowsum(W2) + sum(b2),  v = drug[d]*rel[rel_e]
// neigh[d] = sum over 16 sel edges of score(e)*tail_emb[tail_e]
// y[d]     = [drug[d] | neigh[d]] @ Wc + bc
__global__ __launch_bounds__(256) void k_gather(const int* __restrict__ sel,
                                                const int* __restrict__ dkg,
                                                const void* __restrict__ drug,
                                                const void* __restrict__ rel,
                                                const void* __restrict__ tail,
                                                const void* __restrict__ W1,
                                                const void* __restrict__ b1,
                                                const void* __restrict__ W2,
                                                const void* __restrict__ b2,
                                                const void* __restrict__ Wc,
                                                const void* __restrict__ bc,
                                                const u32* __restrict__ gprobe,
                                                float* __restrict__ y) {
  __shared__ __align__(16) float lwc[128 * 64];   // 32 KB
  __shared__ __align__(16) float vbuf[4][64];
  __shared__ __align__(16) float cat[4][128];
  const bool f32in = (gprobe[0] == F32MAGIC);
  int tid = threadIdx.x, lane = tid & 63, wv = tid >> 6;

  for (int i = tid; i < 128 * 64; i += 256) lwc[i] = ldx(Wc, i, f32in);

  // lane j holds column j of W1 (64 VGPRs), rowsum of W2 row j, b1_j, b2_j
  float w1c[64];
#pragma unroll
  for (int i = 0; i < 64; i++) w1c[i] = ldx(W1, i * 64 + lane, f32in);
  float w2rs = 0.f;
  for (int k = 0; k < 64; k++) w2rs += ldx(W2, lane * 64 + k, f32in);
  float b1j = ldx(b1, lane, f32in);
  float b2j = ldx(b2, lane, f32in);

  int d = blockIdx.x * 4 + wv;
  float dr = ldx(drug, d * 64 + lane, f32in);
  float acc = 0.f;
  __syncthreads();  // lwc staged

#pragma unroll 1
  for (int s = 0; s < SSIZE; s++) {        // uniform trip count for all waves
    int e = sel[d * SSIZE + s];
    int eok = (e >= 0);
    int es = eok ? e : 0;
    int rl = dkg[3 * es + 2];
    int tl = dkg[3 * es + 1];
    float v = dr * ldx(rel, rl * 64 + lane, f32in);
    __syncthreads();                        // prior iteration's vbuf reads done
    vbuf[wv][lane] = v;
    __syncthreads();                        // vbuf visible
    float t = b1j;
#pragma unroll
    for (int i = 0; i < 64; i++) t = fmaf(vbuf[wv][i], w1c[i], t);
    t = 1.f / (1.f + __expf(-t));           // sigmoid
    float c = fmaf(t, w2rs, b2j);
#pragma unroll
    for (int m = 32; m > 0; m >>= 1) c += __shfl_xor(c, m, 64);
    if (eok) acc = fmaf(c, ldx(tail, tl * 64 + lane, f32in), acc);
  }

  cat[wv][lane] = dr;
  cat[wv][64 + lane] = acc;
  __syncthreads();
  float t = ldx(bc, lane, f32in);
#pragma unroll
  for (int i = 0; i < 128; i++) t = fmaf(cat[wv][i], lwc[i * 64 + lane], t);
  y[d * 64 + lane] = t;
}

// ---- Phase 6: per-column mean / inv-std (y is our own f32) ----
__global__ __launch_bounds__(256) void k_stats(const float* __restrict__ y,
                                               float* __restrict__ stats) {
  int j = blockIdx.x;
  int tid = threadIdx.x;
  float s = 0.f, sq = 0.f;
  for (int r = tid; r < NDRUGS; r += 256) {
    float v = y[r * 64 + j];
    s += v;
    sq = fmaf(v, v, sq);
  }
#pragma unroll
  for (int m = 32; m > 0; m >>= 1) { s += __shfl_xor(s, m, 64); sq += __shfl_xor(sq, m, 64); }
  __shared__ float ls[4], lq[4];
  int lane = tid & 63, wv = tid >> 6;
  if (lane == 0) { ls[wv] = s; lq[wv] = sq; }
  __syncthreads();
  if (tid == 0) {
    s = ls[0] + ls[1] + ls[2] + ls[3];
    sq = lq[0] + lq[1] + lq[2] + lq[3];
    float mean = s / (float)NDRUGS;
    float var = sq / (float)NDRUGS - mean * mean;
    stats[j] = mean;
    stats[64 + j] = rsqrtf(var + 1e-5f);
  }
}

// ---- Phase 7: BN + assemble (HFEmbeding | out | X) as FLOAT32 (bf16-quantized
//      values, matching the np reference computed from bf16-cast inputs) ----
__global__ __launch_bounds__(256) void k_final(const void* __restrict__ HFE,
                                               const void* __restrict__ Xv,
                                               const void* __restrict__ gamma,
                                               const void* __restrict__ beta,
                                               const float* __restrict__ y,
                                               const float* __restrict__ stats,
                                               const u32* __restrict__ gprobe,
                                               float* __restrict__ out) {
  const bool f32in = (gprobe[0] == F32MAGIC);
  int i = blockIdx.x * 256 + threadIdx.x;
  if (i < 640000) {
    out[i] = ldx(HFE, i, f32in);                 // bf16-quantized passthrough
  } else if (i < 1280000) {
    int idx = i - 640000;
    int j = idx & 63;
    float m = stats[j], inv = stats[64 + j];
    float g = ldx(gamma, j, f32in), b = ldx(beta, j, f32in);
    out[i] = q16(fmaf(g * (y[idx] - m), inv, b));
  } else if (i < 1290000) {
    out[i] = ldx(Xv, i - 1280000, f32in);        // bf16-quantized passthrough
  }
}

extern "C" void kernel_launch(void* const* d_in, const int* in_sizes, int n_in,
                              void* d_out, int out_size, void* d_ws, size_t ws_size,
                              hipStream_t stream) {
  const void* HFE  = d_in[0];
  const void* Xv   = d_in[1];
  const void* drug = d_in[2];
  const void* rel  = d_in[3];
  const void* tail = d_in[4];
  const void* W1   = d_in[5];
  const void* b1   = d_in[6];
  const void* W2   = d_in[7];
  const void* b2   = d_in[8];
  const void* Wc   = d_in[9];
  const void* bc   = d_in[10];
  const u32*  gam  = (const u32*)d_in[11];   // also the dtype probe (ones)
  const void* bet  = d_in[12];
  const int*  dkg  = (const int*)d_in[13];
  float* out = (float*)d_out;

  // ---- Workspace layout (4.77 MB total; y overlays the dead bucket) ----
  char* w = (char*)d_ws;
  int*   bucket = (int*)(w);                 // [0, 4,000,000)  E ints
  float* y      = (float*)(w);               // reuses bucket after k_select
  int*   sel    = (int*)(w + 4000000);       // 160,000 ints
  int*   deg    = (int*)(w + 4640000);       // 10,000
  int*   cursor = (int*)(w + 4680000);       // 10,000 (adjacent: one memset)
  int*   offs   = (int*)(w + 4720000);       // 10,000
  float* stats  = (float*)(w + 4760000);     // 128

  // Threefry key derivation (seed 42, partitionable split semantics)
  u32 k1x, k1y, k2x, k2y, khx, khy, klx, kly;
  tf2x32(0u, 42u, 0u, 0u, k1x, k1y);   // split(key)[0] -> uniform r
  tf2x32(0u, 42u, 0u, 1u, k2x, k2y);   // split(key)[1] -> randint key
  tf2x32(k2x, k2y, 0u, 0u, khx, khy);  // split(k2)[0] -> higher_bits
  tf2x32(k2x, k2y, 0u, 1u, klx, kly);  // split(k2)[1] -> lower_bits

  hipMemsetAsync(deg, 0, 2 * NDRUGS * sizeof(int), stream);  // deg + cursor
  k_hist<<<(NE + 255) / 256, 256, 0, stream>>>(dkg, deg);
  k_scan<<<1, 1024, 0, stream>>>(deg, offs);
  k_scatter<<<(NE + 255) / 256, 256, 0, stream>>>(dkg, offs, cursor, bucket);
  k_select<<<(NDRUGS + 63) / 64, 64, 0, stream>>>(bucket, deg, offs, sel,
                                                  k1x, k1y, khx, khy, klx, kly);
  k_gather<<<NDRUGS / 4, 256, 0, stream>>>(sel, dkg, drug, rel, tail,
                                           W1, b1, W2, b2, Wc, bc, gam, y);
  k_stats<<<64, 256, 0, stream>>>(y, stats);
  k_final<<<(1290000 + 255) / 256, 256, 0, stream>>>(HFE, Xv, gam, bet, y,
                                                     stats, gam, out);
}

// Round 5
// 459.123 us; speedup vs baseline: 1.1792x; 1.1792x over previous
//
#include <hip/hip_runtime.h>
#include <stdint.h>

// ---- Problem constants ----
#define NDRUGS 10000
#define NTAILS 20000
#define NE     1000000
#define SSIZE  16

typedef unsigned int  u32;
typedef unsigned short u16;
typedef unsigned long long u64;

// ---- Threefry-2x32-20 (exact JAX semantics) ----
__host__ __device__ __forceinline__ void tf2x32(u32 k0, u32 k1, u32 x0, u32 x1,
                                                u32& o0, u32& o1) {
  u32 ks2 = k0 ^ k1 ^ 0x1BD11BDAu;
  x0 += k0; x1 += k1;
#define TFR(r) { x0 += x1; x1 = (x1 << r) | (x1 >> (32 - r)); x1 ^= x0; }
  TFR(13) TFR(15) TFR(26) TFR(6)
  x0 += k1; x1 += ks2 + 1u;
  TFR(17) TFR(29) TFR(16) TFR(24)
  x0 += ks2; x1 += k0 + 2u;
  TFR(13) TFR(15) TFR(26) TFR(6)
  x0 += k0; x1 += k1 + 3u;
  TFR(17) TFR(29) TFR(16) TFR(24)
  x0 += k1; x1 += ks2 + 4u;
  TFR(13) TFR(15) TFR(26) TFR(6)
  x0 += ks2; x1 += k0 + 5u;
#undef TFR
  o0 = x0; o1 = x1;
}

__device__ __forceinline__ u32 rbits32(u32 kx, u32 ky, u32 i) {
  u32 o0, o1;
  tf2x32(kx, ky, 0u, i, o0, o1);
  return o0 ^ o1;   // partitionable fold
}

// ---- bf16-value quantization of f32 (RNE), matching np/jax bf16 cast ----
__device__ __forceinline__ float q16(float f) {
  u32 x = __builtin_bit_cast(u32, f);
  u32 lsb = (x >> 16) & 1u;
  x = (x + 0x7fffu + lsb) & 0xffff0000u;
  return __builtin_bit_cast(float, x);
}

// ---- Phase 1: degree histogram (4 edges/thread, int4 loads) ----
__global__ __launch_bounds__(256) void k_hist(const int4* __restrict__ dkg4,
                                              int* __restrict__ deg) {
  int i = blockIdx.x * 256 + threadIdx.x;
  if (i >= NE / 4) return;
  int4 A = dkg4[3 * i], B = dkg4[3 * i + 1], C = dkg4[3 * i + 2];
  atomicAdd(&deg[A.x], 1);
  atomicAdd(&deg[A.w], 1);
  atomicAdd(&deg[B.z], 1);
  atomicAdd(&deg[C.y], 1);
}

// ---- Phase 2: exclusive scan of degrees (single block) ----
__global__ __launch_bounds__(1024) void k_scan(const int* __restrict__ deg,
                                               int* __restrict__ offsets) {
  __shared__ int part[1024];
  int t = threadIdx.x;
  const int chunk = 10;
  int base = t * chunk;
  int s = 0;
  for (int i = 0; i < chunk; i++) {
    int idx = base + i;
    if (idx < NDRUGS) s += deg[idx];
  }
  part[t] = s;
  __syncthreads();
  for (int off = 1; off < 1024; off <<= 1) {
    int v = (t >= off) ? part[t - off] : 0;
    __syncthreads();
    part[t] += v;
    __syncthreads();
  }
  int run = (t == 0) ? 0 : part[t - 1];
  for (int i = 0; i < chunk; i++) {
    int idx = base + i;
    if (idx < NDRUGS) { offsets[idx] = run; run += deg[idx]; }
  }
}

// ---- Phase 3: bucket edges by head (4 edges/thread) ----
__global__ __launch_bounds__(256) void k_scatter(const int4* __restrict__ dkg4,
                                                 const int* __restrict__ offsets,
                                                 int* __restrict__ cursor,
                                                 int* __restrict__ bucket) {
  int i = blockIdx.x * 256 + threadIdx.x;
  if (i >= NE / 4) return;
  int4 A = dkg4[3 * i], B = dkg4[3 * i + 1], C = dkg4[3 * i + 2];
  int h0 = A.x, h1 = A.w, h2 = B.z, h3 = C.y;
  int e = 4 * i;
  bucket[offsets[h0] + atomicAdd(&cursor[h0], 1)] = e;
  bucket[offsets[h1] + atomicAdd(&cursor[h1], 1)] = e + 1;
  bucket[offsets[h2] + atomicAdd(&cursor[h2], 1)] = e + 2;
  bucket[offsets[h3] + atomicAdd(&cursor[h3], 1)] = e + 3;
}

// ---- Phase 4: per-drug selection of the 16 sampled edges ----
// Key ((rb>>9)<<32)|e reproduces stable lexsort order exactly.
#define SELKEY(e) ((((u64)(rbits32(k1x, k1y, (u32)(e)) >> 9)) << 32) | (u32)(e))
__global__ __launch_bounds__(64) void k_select(const int* __restrict__ bucket,
                                               const int* __restrict__ deg,
                                               const int* __restrict__ offsets,
                                               int* __restrict__ sel,
                                               u32 k1x, u32 k1y,
                                               u32 khx, u32 khy,
                                               u32 klx, u32 kly) {
  __shared__ u64 hp[SSIZE * 64];
  int t = threadIdx.x;
  int d = blockIdx.x * 64 + t;
  if (d >= NDRUGS) return;
  int dg = deg[d], off = offsets[d];
  if (dg <= 0) {
    for (int s = 0; s < SSIZE; s++) sel[d * SSIZE + s] = -1;
    return;
  }
  if (dg >= SSIZE) {
    u64 mx = 0; int mi = 0;
    for (int s = 0; s < SSIZE; s++) {
      int e = bucket[off + s];
      u64 k = SELKEY(e);
      hp[s * 64 + t] = k;
      if (k > mx) { mx = k; mi = s; }
    }
#define SEL_UPD(K)                                             \
    if ((K) < mx) {                                            \
      hp[mi * 64 + t] = (K);                                   \
      mx = 0;                                                  \
      for (int s = 0; s < SSIZE; s++) {                        \
        u64 v = hp[s * 64 + t];                                \
        if (v > mx) { mx = v; mi = s; }                        \
      }                                                        \
    }
    int p = SSIZE;
    for (; p + 4 <= dg; p += 4) {           // 4 independent threefry chains
      int e0 = bucket[off + p],     e1 = bucket[off + p + 1];
      int e2 = bucket[off + p + 2], e3 = bucket[off + p + 3];
      u64 K0 = SELKEY(e0), K1 = SELKEY(e1), K2 = SELKEY(e2), K3 = SELKEY(e3);
      SEL_UPD(K0) SEL_UPD(K1) SEL_UPD(K2) SEL_UPD(K3)
    }
    for (; p < dg; p++) {
      int e = bucket[off + p];
      u64 K = SELKEY(e);
      SEL_UPD(K)
    }
#undef SEL_UPD
    for (int s = 0; s < SSIZE; s++)
      sel[d * SSIZE + s] = (int)(hp[s * 64 + t] & 0xffffffffu);
  } else {
    u64 a[SSIZE];
    for (int i = 0; i < dg; i++) a[i] = SELKEY(bucket[off + i]);
    for (int i = 1; i < dg; i++) {
      u64 v = a[i]; int jj = i - 1;
      while (jj >= 0 && a[jj] > v) { a[jj + 1] = a[jj]; jj--; }
      a[jj + 1] = v;
    }
    for (int i = 0; i < dg; i++) sel[d * SSIZE + i] = (int)(a[i] & 0xffffffffu);
    int need = SSIZE - dg;
    const u32 span = 0x7fffffffu;           // 2^31-1; 2^32 % span = 2
    for (int s = 0; s < need; s++) {
      u32 j = (u32)(d * SSIZE + s);
      u32 hi = rbits32(khx, khy, j) % span;
      u32 lo = rbits32(klx, kly, j) % span;
      u32 u = (hi * 2u + lo) % span;
      int idx = (int)(u % (u32)dg);
      sel[d * SSIZE + dg + s] = (int)(a[idx] & 0xffffffffu);
    }
  }
}

// ---- Phase 5 (fused): edge-MLP score + neighbor gather + concat GEMM ----
// One wave per drug, 4 edges per inner group, no block barriers in the loop.
// y written straight into d_out's Output-1 region.
__global__ __launch_bounds__(256, 2) void k_gather(const int* __restrict__ sel,
                                                   const int* __restrict__ dkg,
                                                   const float* __restrict__ drug,
                                                   const float* __restrict__ rel,
                                                   const float* __restrict__ tail,
                                                   const float* __restrict__ W1,
                                                   const float* __restrict__ b1,
                                                   const float* __restrict__ W2,
                                                   const float* __restrict__ b2,
                                                   const float* __restrict__ Wc,
                                                   const float* __restrict__ bc,
                                                   float* __restrict__ y) {
  __shared__ float rs[64];                        // W2 row-sums (block-shared)
  __shared__ __align__(16) float vb[4][4][64];    // wave, edge-in-group, i
  __shared__ __align__(16) float cat[4][128];
  int tid = threadIdx.x, lane = tid & 63, wv = tid >> 6;

  // Block-cooperative W2 row-sum: coalesced loads + LDS float atomics.
  if (tid < 64) rs[tid] = 0.f;
  __syncthreads();
  for (int r = tid; r < 4096; r += 256) atomicAdd(&rs[r >> 6], q16(W2[r]));
  __syncthreads();
  float w2rs = rs[lane];

  // Per-wave register staging (needs >64 VGPRs -> launch_bounds(256,2)).
  float w1c[64];
#pragma unroll
  for (int i = 0; i < 64; i++) w1c[i] = q16(W1[i * 64 + lane]);
  float b1j = q16(b1[lane]);
  float b2j = q16(b2[lane]);

  int d = blockIdx.x * 4 + wv;
  float dr = q16(drug[d * 64 + lane]);

  // Prefetch sel + dkg for all 16 slots (lanes 0..15), broadcast via shfl.
  int sv = -1, rlv = 0, tlv = 0;
  if (lane < 16) sv = sel[d * SSIZE + lane];
  int es = sv < 0 ? 0 : sv;
  if (lane < 16) { rlv = dkg[3 * es + 2]; tlv = dkg[3 * es + 1]; }

  float acc = 0.f;
#pragma unroll 1
  for (int g = 0; g < 4; g++) {
    int ok[4], tl[4];
    float v[4];
#pragma unroll
    for (int k = 0; k < 4; k++) {
      int sl = g * 4 + k;
      int e = __shfl(sv, sl, 64);
      ok[k] = (e >= 0);
      int rl = __shfl(rlv, sl, 64);
      tl[k] = __shfl(tlv, sl, 64);
      v[k] = dr * q16(rel[rl * 64 + lane]);
    }
#pragma unroll
    for (int k = 0; k < 4; k++) vb[wv][k][lane] = v[k];
    // reads below go through the same LDS object -> compiler orders them
    // after the writes (lgkmcnt); wave-lockstep covers cross-lane visibility.
    float t0 = b1j, t1 = b1j, t2 = b1j, t3 = b1j;
#pragma unroll
    for (int i4 = 0; i4 < 16; i4++) {
      float4 a0 = ((const float4*)vb[wv][0])[i4];
      float4 a1 = ((const float4*)vb[wv][1])[i4];
      float4 a2 = ((const float4*)vb[wv][2])[i4];
      float4 a3 = ((const float4*)vb[wv][3])[i4];
      t0 = fmaf(a0.x, w1c[4*i4+0], t0); t0 = fmaf(a0.y, w1c[4*i4+1], t0);
      t0 = fmaf(a0.z, w1c[4*i4+2], t0); t0 = fmaf(a0.w, w1c[4*i4+3], t0);
      t1 = fmaf(a1.x, w1c[4*i4+0], t1); t1 = fmaf(a1.y, w1c[4*i4+1], t1);
      t1 = fmaf(a1.z, w1c[4*i4+2], t1); t1 = fmaf(a1.w, w1c[4*i4+3], t1);
      t2 = fmaf(a2.x, w1c[4*i4+0], t2); t2 = fmaf(a2.y, w1c[4*i4+1], t2);
      t2 = fmaf(a2.z, w1c[4*i4+2], t2); t2 = fmaf(a2.w, w1c[4*i4+3], t2);
      t3 = fmaf(a3.x, w1c[4*i4+0], t3); t3 = fmaf(a3.y, w1c[4*i4+1], t3);
      t3 = fmaf(a3.z, w1c[4*i4+2], t3); t3 = fmaf(a3.w, w1c[4*i4+3], t3);
    }
    t0 = 1.f / (1.f + __expf(-t0));
    t1 = 1.f / (1.f + __expf(-t1));
    t2 = 1.f / (1.f + __expf(-t2));
    t3 = 1.f / (1.f + __expf(-t3));
    float c0 = fmaf(t0, w2rs, b2j), c1 = fmaf(t1, w2rs, b2j);
    float c2 = fmaf(t2, w2rs, b2j), c3 = fmaf(t3, w2rs, b2j);
#pragma unroll
    for (int m = 32; m; m >>= 1) {        // 4 interleaved wave reductions
      c0 += __shfl_xor(c0, m, 64); c1 += __shfl_xor(c1, m, 64);
      c2 += __shfl_xor(c2, m, 64); c3 += __shfl_xor(c3, m, 64);
    }
    if (ok[0]) acc = fmaf(c0, q16(tail[tl[0] * 64 + lane]), acc);
    if (ok[1]) acc = fmaf(c1, q16(tail[tl[1] * 64 + lane]), acc);
    if (ok[2]) acc = fmaf(c2, q16(tail[tl[2] * 64 + lane]), acc);
    if (ok[3]) acc = fmaf(c3, q16(tail[tl[3] * 64 + lane]), acc);
  }

  // Epilogue: y = [dr | acc] @ Wc + bc  (Wc read from global, L1/L2-hot)
  cat[wv][lane] = dr;
  cat[wv][64 + lane] = acc;
  float t = q16(bc[lane]);
#pragma unroll
  for (int i4 = 0; i4 < 32; i4++) {
    float4 a = ((const float4*)cat[wv])[i4];
    t = fmaf(a.x, q16(Wc[(4*i4+0) * 64 + lane]), t);
    t = fmaf(a.y, q16(Wc[(4*i4+1) * 64 + lane]), t);
    t = fmaf(a.z, q16(Wc[(4*i4+2) * 64 + lane]), t);
    t = fmaf(a.w, q16(Wc[(4*i4+3) * 64 + lane]), t);
  }
  y[d * 64 + lane] = t;
}

// ---- Phase 6a: coalesced per-block column partial sums ----
__global__ __launch_bounds__(256) void k_stats1(const float* __restrict__ y,
                                                float* __restrict__ ps,
                                                float* __restrict__ pq) {
  __shared__ float S[4][64], Q[4][64];
  int b = blockIdx.x;
  int tid = threadIdx.x, c = tid & 63, rsub = tid >> 6;
  float s = 0.f, q = 0.f;
  int r0 = b * 100;
  for (int rr = rsub; rr < 100; rr += 4) {
    float v = y[(r0 + rr) * 64 + c];
    s += v;
    q = fmaf(v, v, q);
  }
  S[rsub][c] = s; Q[rsub][c] = q;
  __syncthreads();
  if (tid < 64) {
    s = S[0][tid] + S[1][tid] + S[2][tid] + S[3][tid];
    q = Q[0][tid] + Q[1][tid] + Q[2][tid] + Q[3][tid];
    ps[b * 64 + tid] = s;
    pq[b * 64 + tid] = q;
  }
}

// ---- Phase 6b: finalize mean / inv-std ----
__global__ __launch_bounds__(64) void k_stats2(const float* __restrict__ ps,
                                               const float* __restrict__ pq,
                                               float* __restrict__ stats) {
  int c = threadIdx.x;
  float s = 0.f, q = 0.f;
  for (int b = 0; b < 100; b++) { s += ps[b * 64 + c]; q += pq[b * 64 + c]; }
  float mean = s / (float)NDRUGS;
  float var = q / (float)NDRUGS - mean * mean;
  stats[c] = mean;
  stats[64 + c] = rsqrtf(var + 1e-5f);
}

// ---- Phase 7: BN (in place) + passthrough copies, float4 ----
__global__ __launch_bounds__(256) void k_final(const float4* __restrict__ HFE4,
                                               const float4* __restrict__ Xv4,
                                               const float* __restrict__ gamma,
                                               const float* __restrict__ beta,
                                               const float* __restrict__ stats,
                                               float4* __restrict__ out4) {
  int i4 = blockIdx.x * 256 + threadIdx.x;
  if (i4 < 160000) {
    float4 a = HFE4[i4];
    a.x = q16(a.x); a.y = q16(a.y); a.z = q16(a.z); a.w = q16(a.w);
    out4[i4] = a;
  } else if (i4 < 320000) {
    int idx4 = i4 - 160000;
    int j0 = (idx4 * 4) & 63;
    float4 v = out4[i4];                      // y, in place
    float4 r;
    r.x = q16(fmaf(q16(gamma[j0+0]) * (v.x - stats[j0+0]), stats[64+j0+0], q16(beta[j0+0])));
    r.y = q16(fmaf(q16(gamma[j0+1]) * (v.y - stats[j0+1]), stats[64+j0+1], q16(beta[j0+1])));
    r.z = q16(fmaf(q16(gamma[j0+2]) * (v.z - stats[j0+2]), stats[64+j0+2], q16(beta[j0+2])));
    r.w = q16(fmaf(q16(gamma[j0+3]) * (v.w - stats[j0+3]), stats[64+j0+3], q16(beta[j0+3])));
    out4[i4] = r;
  } else if (i4 < 322500) {
    float4 a = Xv4[i4 - 320000];
    a.x = q16(a.x); a.y = q16(a.y); a.z = q16(a.z); a.w = q16(a.w);
    out4[i4] = a;
  }
}

extern "C" void kernel_launch(void* const* d_in, const int* in_sizes, int n_in,
                              void* d_out, int out_size, void* d_ws, size_t ws_size,
                              hipStream_t stream) {
  const float* HFE  = (const float*)d_in[0];
  const float* Xv   = (const float*)d_in[1];
  const float* drug = (const float*)d_in[2];
  const float* rel  = (const float*)d_in[3];
  const float* tail = (const float*)d_in[4];
  const float* W1   = (const float*)d_in[5];
  const float* b1   = (const float*)d_in[6];
  const float* W2   = (const float*)d_in[7];
  const float* b2   = (const float*)d_in[8];
  const float* Wc   = (const float*)d_in[9];
  const float* bc   = (const float*)d_in[10];
  const float* gam  = (const float*)d_in[11];
  const float* bet  = (const float*)d_in[12];
  const int*   dkg  = (const int*)d_in[13];
  float* out = (float*)d_out;
  float* y = out + 640000;                   // Output-1 region doubles as y

  // ---- Workspace (proven footprint <= 4,760,512 B) ----
  char* w = (char*)d_ws;
  int*   bucket = (int*)(w);                 // E ints; dead after k_select
  float* ps     = (float*)(w);               // 100*64 f32, overlays dead bucket
  float* pq     = (float*)(w + 25600);       // 100*64 f32
  int*   sel    = (int*)(w + 4000000);       // 160,000 ints
  int*   deg    = (int*)(w + 4640000);       // 10,000
  int*   cursor = (int*)(w + 4680000);       // 10,000
  int*   offs   = (int*)(w + 4720000);       // 10,000
  float* stats  = (float*)(w + 4760000);     // 128

  // Threefry key derivation (seed 42, partitionable split semantics)
  u32 k1x, k1y, k2x, k2y, khx, khy, klx, kly;
  tf2x32(0u, 42u, 0u, 0u, k1x, k1y);   // split(key)[0] -> uniform r
  tf2x32(0u, 42u, 0u, 1u, k2x, k2y);   // split(key)[1] -> randint key
  tf2x32(k2x, k2y, 0u, 0u, khx, khy);  // split(k2)[0] -> higher_bits
  tf2x32(k2x, k2y, 0u, 1u, klx, kly);  // split(k2)[1] -> lower_bits

  hipMemsetAsync(deg, 0, 2 * NDRUGS * sizeof(int), stream);  // deg + cursor
  k_hist<<<(NE / 4 + 255) / 256, 256, 0, stream>>>((const int4*)dkg, deg);
  k_scan<<<1, 1024, 0, stream>>>(deg, offs);
  k_scatter<<<(NE / 4 + 255) / 256, 256, 0, stream>>>((const int4*)dkg, offs,
                                                      cursor, bucket);
  k_select<<<(NDRUGS + 63) / 64, 64, 0, stream>>>(bucket, deg, offs, sel,
                                                  k1x, k1y, khx, khy, klx, kly);
  k_gather<<<NDRUGS / 4, 256, 0, stream>>>(sel, dkg, drug, rel, tail,
                                           W1, b1, W2, b2, Wc, bc, y);
  k_stats1<<<100, 256, 0, stream>>>(y, ps, pq);
  k_stats2<<<1, 64, 0, stream>>>(ps, pq, stats);
  k_final<<<(322500 + 255) / 256, 256, 0, stream>>>((const float4*)HFE,
                                                    (const float4*)Xv,
                                                    gam, bet, stats,
                                                    (float4*)out);
}

// Round 6
// 410.751 us; speedup vs baseline: 1.3181x; 1.1178x over previous
//
#include <hip/hip_runtime.h>
#include <stdint.h>

// ---- Problem constants ----
#define NDRUGS 10000
#define NTAILS 20000
#define NE     1000000
#define SSIZE  16
#define SH     10240        // shard stride (ints) for deg/cursor shards

typedef unsigned int  u32;
typedef unsigned short u16;
typedef unsigned long long u64;

// ---- Threefry-2x32-20 (exact JAX semantics) ----
__host__ __device__ __forceinline__ void tf2x32(u32 k0, u32 k1, u32 x0, u32 x1,
                                                u32& o0, u32& o1) {
  u32 ks2 = k0 ^ k1 ^ 0x1BD11BDAu;
  x0 += k0; x1 += k1;
#define TFR(r) { x0 += x1; x1 = (x1 << r) | (x1 >> (32 - r)); x1 ^= x0; }
  TFR(13) TFR(15) TFR(26) TFR(6)
  x0 += k1; x1 += ks2 + 1u;
  TFR(17) TFR(29) TFR(16) TFR(24)
  x0 += ks2; x1 += k0 + 2u;
  TFR(13) TFR(15) TFR(26) TFR(6)
  x0 += k0; x1 += k1 + 3u;
  TFR(17) TFR(29) TFR(16) TFR(24)
  x0 += k1; x1 += ks2 + 4u;
  TFR(13) TFR(15) TFR(26) TFR(6)
  x0 += ks2; x1 += k0 + 5u;
#undef TFR
  o0 = x0; o1 = x1;
}

__device__ __forceinline__ u32 rbits32(u32 kx, u32 ky, u32 i) {
  u32 o0, o1;
  tf2x32(kx, ky, 0u, i, o0, o1);
  return o0 ^ o1;   // partitionable fold
}

// ---- bf16-value quantization of f32 (RNE), matching np/jax bf16 cast ----
__device__ __forceinline__ float q16(float f) {
  u32 x = __builtin_bit_cast(u32, f);
  u32 lsb = (x >> 16) & 1u;
  x = (x + 0x7fffu + lsb) & 0xffff0000u;
  return __builtin_bit_cast(float, x);
}

// ---- Phase 1: degree histogram, 4-way sharded counters ----
__global__ __launch_bounds__(256) void k_hist(const int4* __restrict__ dkg4,
                                              int* __restrict__ degs) {
  int i = blockIdx.x * 256 + threadIdx.x;
  if (i >= NE / 4) return;
  int4 A = dkg4[3 * i], B = dkg4[3 * i + 1], C = dkg4[3 * i + 2];
  int s = (threadIdx.x & 3) * SH;
  atomicAdd(&degs[s + A.x], 1);
  atomicAdd(&degs[s + A.w], 1);
  atomicAdd(&degs[s + B.z], 1);
  atomicAdd(&degs[s + C.y], 1);
}

// ---- Phase 2: merge shards + exclusive scan + per-shard cursor bases ----
__global__ __launch_bounds__(1024) void k_scan(const int* __restrict__ degs,
                                               int* __restrict__ deg,
                                               int* __restrict__ offsets,
                                               int* __restrict__ curs) {
  __shared__ int part[1024];
  int t = threadIdx.x;
  const int chunk = 10;
  int base = t * chunk;
  int s = 0;
  for (int i = 0; i < chunk; i++) {
    int idx = base + i;
    if (idx < NDRUGS)
      s += degs[idx] + degs[SH + idx] + degs[2 * SH + idx] + degs[3 * SH + idx];
  }
  part[t] = s;
  __syncthreads();
  for (int off = 1; off < 1024; off <<= 1) {
    int v = (t >= off) ? part[t - off] : 0;
    __syncthreads();
    part[t] += v;
    __syncthreads();
  }
  int run = (t == 0) ? 0 : part[t - 1];
  for (int i = 0; i < chunk; i++) {
    int idx = base + i;
    if (idx < NDRUGS) {
      int d0 = degs[idx], d1 = degs[SH + idx];
      int d2 = degs[2 * SH + idx], d3 = degs[3 * SH + idx];
      int dg = d0 + d1 + d2 + d3;
      deg[idx] = dg;
      offsets[idx] = run;
      curs[idx] = run;
      curs[SH + idx] = run + d0;
      curs[2 * SH + idx] = run + d0 + d1;
      curs[3 * SH + idx] = run + d0 + d1 + d2;
      run += dg;
    }
  }
}

// ---- Phase 3: bucket edges by head, sharded cursors ----
__global__ __launch_bounds__(256) void k_scatter(const int4* __restrict__ dkg4,
                                                 int* __restrict__ curs,
                                                 int* __restrict__ bucket) {
  int i = blockIdx.x * 256 + threadIdx.x;
  if (i >= NE / 4) return;
  int4 A = dkg4[3 * i], B = dkg4[3 * i + 1], C = dkg4[3 * i + 2];
  int s = (threadIdx.x & 3) * SH;
  int e = 4 * i;
  bucket[atomicAdd(&curs[s + A.x], 1)] = e;
  bucket[atomicAdd(&curs[s + A.w], 1)] = e + 1;
  bucket[atomicAdd(&curs[s + B.z], 1)] = e + 2;
  bucket[atomicAdd(&curs[s + C.y], 1)] = e + 3;
}

// ---- Phase 4: per-drug selection of the 16 sampled edges ----
// Key ((rb>>9)<<32)|e reproduces stable lexsort order exactly; top-16 smallest.
#define SELKEY(e) ((((u64)(rbits32(k1x, k1y, (u32)(e)) >> 9)) << 32) | (u32)(e))
__global__ __launch_bounds__(64) void k_select(const int* __restrict__ bucket,
                                               const int* __restrict__ deg,
                                               const int* __restrict__ offsets,
                                               int* __restrict__ sel,
                                               u32 k1x, u32 k1y,
                                               u32 khx, u32 khy,
                                               u32 klx, u32 kly) {
  __shared__ u64 hp[SSIZE * 64];
  int t = threadIdx.x;
  int d = blockIdx.x * 64 + t;
  if (d >= NDRUGS) return;
  int dg = deg[d], off = offsets[d];
  if (dg <= 0) {
    for (int s = 0; s < SSIZE; s++) sel[d * SSIZE + s] = -1;
    return;
  }
  if (dg >= SSIZE) {
    u64 mx = 0; int mi = 0;
    for (int s = 0; s < SSIZE; s++) {
      int e = bucket[off + s];
      u64 k = SELKEY(e);
      hp[s * 64 + t] = k;
      if (k > mx) { mx = k; mi = s; }
    }
#define SEL_UPD(K)                                             \
    if ((K) < mx) {                                            \
      hp[mi * 64 + t] = (K);                                   \
      mx = 0;                                                  \
      for (int s = 0; s < SSIZE; s++) {                        \
        u64 v = hp[s * 64 + t];                                \
        if (v > mx) { mx = v; mi = s; }                        \
      }                                                        \
    }
    int p = SSIZE;
    for (; p + 8 <= dg; p += 8) {           // 8 independent threefry chains
      int e0 = bucket[off + p],     e1 = bucket[off + p + 1];
      int e2 = bucket[off + p + 2], e3 = bucket[off + p + 3];
      int e4 = bucket[off + p + 4], e5 = bucket[off + p + 5];
      int e6 = bucket[off + p + 6], e7 = bucket[off + p + 7];
      u64 K0 = SELKEY(e0), K1 = SELKEY(e1), K2 = SELKEY(e2), K3 = SELKEY(e3);
      u64 K4 = SELKEY(e4), K5 = SELKEY(e5), K6 = SELKEY(e6), K7 = SELKEY(e7);
      SEL_UPD(K0) SEL_UPD(K1) SEL_UPD(K2) SEL_UPD(K3)
      SEL_UPD(K4) SEL_UPD(K5) SEL_UPD(K6) SEL_UPD(K7)
    }
    for (; p < dg; p++) {
      int e = bucket[off + p];
      u64 K = SELKEY(e);
      SEL_UPD(K)
    }
#undef SEL_UPD
    for (int s = 0; s < SSIZE; s++)
      sel[d * SSIZE + s] = (int)(hp[s * 64 + t] & 0xffffffffu);
  } else {
    u64 a[SSIZE];
    for (int i = 0; i < dg; i++) a[i] = SELKEY(bucket[off + i]);
    for (int i = 1; i < dg; i++) {
      u64 v = a[i]; int jj = i - 1;
      while (jj >= 0 && a[jj] > v) { a[jj + 1] = a[jj]; jj--; }
      a[jj + 1] = v;
    }
    for (int i = 0; i < dg; i++) sel[d * SSIZE + i] = (int)(a[i] & 0xffffffffu);
    int need = SSIZE - dg;
    const u32 span = 0x7fffffffu;           // 2^31-1; 2^32 % span = 2
    for (int s = 0; s < need; s++) {
      u32 j = (u32)(d * SSIZE + s);
      u32 hi = rbits32(khx, khy, j) % span;
      u32 lo = rbits32(klx, kly, j) % span;
      u32 u = (hi * 2u + lo) % span;
      int idx = (int)(u % (u32)dg);
      sel[d * SSIZE + dg + s] = (int)(a[idx] & 0xffffffffu);
    }
  }
}

// ---- Phase 5 (fused, persistent waves): edge-MLP + gather + concat GEMM ----
// 625 blocks x 4 waves; each wave owns 4 drugs. W1 column in VGPRs, Wc
// pre-quantized in LDS, W2 rowsum in LDS -- all staged once and amortized.
// Per drug: all 16 edges in one straight-line pipeline (16 gathers in
// flight, 16 interleaved FMA chains, batched shfl reductions).
__global__ __launch_bounds__(256, 2) void k_gather(const int* __restrict__ sel,
                                                   const int* __restrict__ dkg,
                                                   const float* __restrict__ drug,
                                                   const float* __restrict__ rel,
                                                   const float* __restrict__ tail,
                                                   const float* __restrict__ W1,
                                                   const float* __restrict__ b1,
                                                   const float* __restrict__ W2,
                                                   const float* __restrict__ b2,
                                                   const float* __restrict__ Wc,
                                                   const float* __restrict__ bc,
                                                   float* __restrict__ y) {
  __shared__ __align__(16) float lwc[128 * 64];     // 32 KB, q16'd Wc
  __shared__ float rs[64];                          // W2 row-sums
  __shared__ __align__(16) float vb[4][16][64];     // 16 KB: wave, edge, dim
  __shared__ __align__(16) float cat[4][128];       // 2 KB
  int tid = threadIdx.x, lane = tid & 63, wv = tid >> 6;

  for (int i = tid; i < 8192; i += 256) lwc[i] = q16(Wc[i]);
  if (tid < 64) {                                   // deterministic rowsum
    float s = 0.f;
    for (int k = 0; k < 64; k++) s += q16(W2[tid * 64 + k]);
    rs[tid] = s;
  }
  __syncthreads();
  float w2rs = rs[lane];

  float w1c[64];
#pragma unroll
  for (int i = 0; i < 64; i++) w1c[i] = q16(W1[i * 64 + lane]);
  float b1j = q16(b1[lane]);
  float b2j = q16(b2[lane]);

  int d0 = (blockIdx.x * 4 + wv) * 4;               // 4 drugs per wave
  // Prefetch sel + dkg for 4 drugs x 16 slots across the 64 lanes.
  int sv = sel[d0 * SSIZE + lane];
  int es = sv < 0 ? 0 : sv;
  int rlv = dkg[3 * es + 2];
  int tlv = dkg[3 * es + 1];

#pragma unroll 1
  for (int dd = 0; dd < 4; dd++) {
    int d = d0 + dd;
    float dr = q16(drug[d * 64 + lane]);

    // 16 independent rel gathers -> LDS broadcast buffer
#pragma unroll
    for (int k = 0; k < 16; k++) {
      int rl = __shfl(rlv, dd * 16 + k, 64);
      vb[wv][k][lane] = dr * q16(rel[rl * 64 + lane]);
    }
    // 16 interleaved 64-FMA chains (uniform-address b128 LDS broadcasts)
    float t[16];
#pragma unroll
    for (int k = 0; k < 16; k++) t[k] = b1j;
#pragma unroll
    for (int i4 = 0; i4 < 16; i4++) {
      float w0 = w1c[4 * i4], w1_ = w1c[4 * i4 + 1];
      float w2_ = w1c[4 * i4 + 2], w3 = w1c[4 * i4 + 3];
#pragma unroll
      for (int k = 0; k < 16; k++) {
        float4 a = ((const float4*)vb[wv][k])[i4];
        t[k] = fmaf(a.x, w0, t[k]);
        t[k] = fmaf(a.y, w1_, t[k]);
        t[k] = fmaf(a.z, w2_, t[k]);
        t[k] = fmaf(a.w, w3, t[k]);
      }
    }
    // sigmoid + per-lane contribution, then 16 batched wave reductions
#pragma unroll
    for (int k = 0; k < 16; k++) {
      t[k] = 1.f / (1.f + __expf(-t[k]));
      t[k] = fmaf(t[k], w2rs, b2j);
    }
#pragma unroll
    for (int m = 32; m; m >>= 1) {
#pragma unroll
      for (int k = 0; k < 16; k++) t[k] += __shfl_xor(t[k], m, 64);
    }
    // 16 tail gathers into 4 independent acc chains
    float a0 = 0.f, a1 = 0.f, a2 = 0.f, a3 = 0.f;
#pragma unroll
    for (int k = 0; k < 16; k += 4) {
      int sl = dd * 16 + k;
      int e0 = __shfl(sv, sl, 64),     e1 = __shfl(sv, sl + 1, 64);
      int e2 = __shfl(sv, sl + 2, 64), e3 = __shfl(sv, sl + 3, 64);
      int t0 = __shfl(tlv, sl, 64),     t1 = __shfl(tlv, sl + 1, 64);
      int t2 = __shfl(tlv, sl + 2, 64), t3 = __shfl(tlv, sl + 3, 64);
      if (e0 >= 0) a0 = fmaf(t[k],     q16(tail[t0 * 64 + lane]), a0);
      if (e1 >= 0) a1 = fmaf(t[k + 1], q16(tail[t1 * 64 + lane]), a1);
      if (e2 >= 0) a2 = fmaf(t[k + 2], q16(tail[t2 * 64 + lane]), a2);
      if (e3 >= 0) a3 = fmaf(t[k + 3], q16(tail[t3 * 64 + lane]), a3);
    }
    float acc = (a0 + a1) + (a2 + a3);

    // epilogue: y = [dr | acc] @ Wc + bc  (Wc from LDS, pre-quantized)
    cat[wv][lane] = dr;
    cat[wv][64 + lane] = acc;
    float o = q16(bc[lane]);
#pragma unroll
    for (int i4 = 0; i4 < 32; i4++) {
      float4 a = ((const float4*)cat[wv])[i4];
      o = fmaf(a.x, lwc[(4 * i4 + 0) * 64 + lane], o);
      o = fmaf(a.y, lwc[(4 * i4 + 1) * 64 + lane], o);
      o = fmaf(a.z, lwc[(4 * i4 + 2) * 64 + lane], o);
      o = fmaf(a.w, lwc[(4 * i4 + 3) * 64 + lane], o);
    }
    y[d * 64 + lane] = o;
  }
}

// ---- Phase 6a: coalesced per-block column partial sums ----
__global__ __launch_bounds__(256) void k_stats1(const float* __restrict__ y,
                                                float* __restrict__ ps,
                                                float* __restrict__ pq) {
  __shared__ float S[4][64], Q[4][64];
  int b = blockIdx.x;
  int tid = threadIdx.x, c = tid & 63, rsub = tid >> 6;
  float s = 0.f, q = 0.f;
  int r0 = b * 100;
  for (int rr = rsub; rr < 100; rr += 4) {
    float v = y[(r0 + rr) * 64 + c];
    s += v;
    q = fmaf(v, v, q);
  }
  S[rsub][c] = s; Q[rsub][c] = q;
  __syncthreads();
  if (tid < 64) {
    s = S[0][tid] + S[1][tid] + S[2][tid] + S[3][tid];
    q = Q[0][tid] + Q[1][tid] + Q[2][tid] + Q[3][tid];
    ps[b * 64 + tid] = s;
    pq[b * 64 + tid] = q;
  }
}

// ---- Phase 6b: finalize mean / inv-std ----
__global__ __launch_bounds__(64) void k_stats2(const float* __restrict__ ps,
                                               const float* __restrict__ pq,
                                               float* __restrict__ stats) {
  int c = threadIdx.x;
  float s = 0.f, q = 0.f;
  for (int b = 0; b < 100; b++) { s += ps[b * 64 + c]; q += pq[b * 64 + c]; }
  float mean = s / (float)NDRUGS;
  float var = q / (float)NDRUGS - mean * mean;
  stats[c] = mean;
  stats[64 + c] = rsqrtf(var + 1e-5f);
}

// ---- Phase 7: BN (in place) + passthrough copies, float4 ----
__global__ __launch_bounds__(256) void k_final(const float4* __restrict__ HFE4,
                                               const float4* __restrict__ Xv4,
                                               const float* __restrict__ gamma,
                                               const float* __restrict__ beta,
                                               const float* __restrict__ stats,
                                               float4* __restrict__ out4) {
  int i4 = blockIdx.x * 256 + threadIdx.x;
  if (i4 < 160000) {
    float4 a = HFE4[i4];
    a.x = q16(a.x); a.y = q16(a.y); a.z = q16(a.z); a.w = q16(a.w);
    out4[i4] = a;
  } else if (i4 < 320000) {
    int idx4 = i4 - 160000;
    int j0 = (idx4 * 4) & 63;
    float4 v = out4[i4];                      // y, in place
    float4 r;
    r.x = q16(fmaf(q16(gamma[j0+0]) * (v.x - stats[j0+0]), stats[64+j0+0], q16(beta[j0+0])));
    r.y = q16(fmaf(q16(gamma[j0+1]) * (v.y - stats[j0+1]), stats[64+j0+1], q16(beta[j0+1])));
    r.z = q16(fmaf(q16(gamma[j0+2]) * (v.z - stats[j0+2]), stats[64+j0+2], q16(beta[j0+2])));
    r.w = q16(fmaf(q16(gamma[j0+3]) * (v.w - stats[j0+3]), stats[64+j0+3], q16(beta[j0+3])));
    out4[i4] = r;
  } else if (i4 < 322500) {
    float4 a = Xv4[i4 - 320000];
    a.x = q16(a.x); a.y = q16(a.y); a.z = q16(a.z); a.w = q16(a.w);
    out4[i4] = a;
  }
}

extern "C" void kernel_launch(void* const* d_in, const int* in_sizes, int n_in,
                              void* d_out, int out_size, void* d_ws, size_t ws_size,
                              hipStream_t stream) {
  const float* drug = (const float*)d_in[2];
  const float* rel  = (const float*)d_in[3];
  const float* tail = (const float*)d_in[4];
  const float* W1   = (const float*)d_in[5];
  const float* b1   = (const float*)d_in[6];
  const float* W2   = (const float*)d_in[7];
  const float* b2   = (const float*)d_in[8];
  const float* Wc   = (const float*)d_in[9];
  const float* bc   = (const float*)d_in[10];
  const float* gam  = (const float*)d_in[11];
  const float* bet  = (const float*)d_in[12];
  const int*   dkg  = (const int*)d_in[13];
  float* out = (float*)d_out;
  float* y = out + 640000;                   // Output-1 region doubles as y

  // ---- Workspace (footprint unchanged: <= 4,760,512 B) ----
  char* w = (char*)d_ws;
  int*   bucket = (int*)(w);                 // E ints; dead after k_select
  float* ps     = (float*)(w);               // overlays dead bucket
  float* pq     = (float*)(w + 25600);
  int*   degs   = (int*)(w + 4000000);       // 4 x SH shard histograms
  int*   curs   = (int*)(w + 4163840);       // 4 x SH shard cursors
  int*   sel    = (int*)(w + 4000000);       // overlays degs/curs after scatter
  int*   deg    = (int*)(w + 4640000);       // 10,000
  int*   offs   = (int*)(w + 4720000);       // 10,000
  float* stats  = (float*)(w + 4760000);     // 128

  // Threefry key derivation (seed 42, partitionable split semantics)
  u32 k1x, k1y, k2x, k2y, khx, khy, klx, kly;
  tf2x32(0u, 42u, 0u, 0u, k1x, k1y);   // split(key)[0] -> uniform r
  tf2x32(0u, 42u, 0u, 1u, k2x, k2y);   // split(key)[1] -> randint key
  tf2x32(k2x, k2y, 0u, 0u, khx, khy);  // split(k2)[0] -> higher_bits
  tf2x32(k2x, k2y, 0u, 1u, klx, kly);  // split(k2)[1] -> lower_bits

  hipMemsetAsync(degs, 0, 4 * SH * sizeof(int), stream);
  k_hist<<<(NE / 4 + 255) / 256, 256, 0, stream>>>((const int4*)dkg, degs);
  k_scan<<<1, 1024, 0, stream>>>(degs, deg, offs, curs);
  k_scatter<<<(NE / 4 + 255) / 256, 256, 0, stream>>>((const int4*)dkg, curs,
                                                      bucket);
  k_select<<<(NDRUGS + 63) / 64, 64, 0, stream>>>(bucket, deg, offs, sel,
                                                  k1x, k1y, khx, khy, klx, kly);
  k_gather<<<625, 256, 0, stream>>>(sel, dkg, drug, rel, tail,
                                    W1, b1, W2, b2, Wc, bc, y);
  k_stats1<<<100, 256, 0, stream>>>(y, ps, pq);
  k_stats2<<<1, 64, 0, stream>>>(ps, pq, stats);
  k_final<<<(322500 + 255) / 256, 256, 0, stream>>>((const float4*)d_in[0],
                                                    (const float4*)d_in[1],
                                                    gam, bet, stats,
                                                    (float4*)out);
}

// Round 7
// 311.300 us; speedup vs baseline: 1.7392x; 1.3195x over previous
//
#include <hip/hip_runtime.h>
#include <stdint.h>

// ---- Problem constants ----
#define NDRUGS 10000
#define NTAILS 20000
#define NE     1000000
#define SSIZE  16
#define SH     10240        // shard stride (ints) for deg/cursor shards

typedef unsigned int  u32;
typedef unsigned short u16;
typedef unsigned long long u64;
typedef __attribute__((ext_vector_type(8))) short bf16x8;
typedef __attribute__((ext_vector_type(4))) float f32x4;
#define U64MAX 0xffffffffffffffffULL

// ---- Threefry-2x32-20 (exact JAX semantics) ----
__host__ __device__ __forceinline__ void tf2x32(u32 k0, u32 k1, u32 x0, u32 x1,
                                                u32& o0, u32& o1) {
  u32 ks2 = k0 ^ k1 ^ 0x1BD11BDAu;
  x0 += k0; x1 += k1;
#define TFR(r) { x0 += x1; x1 = (x1 << r) | (x1 >> (32 - r)); x1 ^= x0; }
  TFR(13) TFR(15) TFR(26) TFR(6)
  x0 += k1; x1 += ks2 + 1u;
  TFR(17) TFR(29) TFR(16) TFR(24)
  x0 += ks2; x1 += k0 + 2u;
  TFR(13) TFR(15) TFR(26) TFR(6)
  x0 += k0; x1 += k1 + 3u;
  TFR(17) TFR(29) TFR(16) TFR(24)
  x0 += k1; x1 += ks2 + 4u;
  TFR(13) TFR(15) TFR(26) TFR(6)
  x0 += ks2; x1 += k0 + 5u;
#undef TFR
  o0 = x0; o1 = x1;
}

__device__ __forceinline__ u32 rbits32(u32 kx, u32 ky, u32 i) {
  u32 o0, o1;
  tf2x32(kx, ky, 0u, i, o0, o1);
  return o0 ^ o1;   // partitionable fold
}

// ---- bf16 helpers (RNE, matches np/jax bf16 cast) ----
__device__ __forceinline__ float q16(float f) {
  u32 x = __builtin_bit_cast(u32, f);
  u32 lsb = (x >> 16) & 1u;
  x = (x + 0x7fffu + lsb) & 0xffff0000u;
  return __builtin_bit_cast(float, x);
}
__device__ __forceinline__ u16 rne16(float f) {    // f32 -> bf16 bits (RNE)
  u32 x = __builtin_bit_cast(u32, f);
  u32 lsb = (x >> 16) & 1u;
  return (u16)((x + 0x7fffu + lsb) >> 16);
}
__device__ __forceinline__ float bfbits2f(u16 b) {
  u32 x = ((u32)b) << 16;
  return __builtin_bit_cast(float, x);
}

// ---- Phase 1: degree histogram, 4-way sharded counters ----
__global__ __launch_bounds__(256) void k_hist(const int4* __restrict__ dkg4,
                                              int* __restrict__ degs) {
  int i = blockIdx.x * 256 + threadIdx.x;
  if (i >= NE / 4) return;
  int4 A = dkg4[3 * i], B = dkg4[3 * i + 1], C = dkg4[3 * i + 2];
  int s = (threadIdx.x & 3) * SH;
  atomicAdd(&degs[s + A.x], 1);
  atomicAdd(&degs[s + A.w], 1);
  atomicAdd(&degs[s + B.z], 1);
  atomicAdd(&degs[s + C.y], 1);
}

// ---- Phase 2: merge shards + exclusive scan (shfl-based, 1 barrier) ----
__global__ __launch_bounds__(1024) void k_scan(const int* __restrict__ degs,
                                               int* __restrict__ deg,
                                               int* __restrict__ offsets,
                                               int* __restrict__ curs) {
  __shared__ int wsum[16];
  int t = threadIdx.x, lane = t & 63, w = t >> 6;
  int base = t * 10;
  int s = 0;
  for (int i = 0; i < 10; i++) {
    int idx = base + i;
    if (idx < NDRUGS)
      s += degs[idx] + degs[SH + idx] + degs[2 * SH + idx] + degs[3 * SH + idx];
  }
  int sc = s;                                  // inclusive wave scan
#pragma unroll
  for (int ofs = 1; ofs < 64; ofs <<= 1) {
    int v = __shfl_up(sc, ofs, 64);
    if (lane >= ofs) sc += v;
  }
  if (lane == 63) wsum[w] = sc;
  __syncthreads();
  int woff = 0;
#pragma unroll
  for (int i = 0; i < 16; i++)
    if (i < w) woff += wsum[i];
  int run = woff + sc - s;                     // exclusive prefix for chunk
  for (int i = 0; i < 10; i++) {
    int idx = base + i;
    if (idx < NDRUGS) {
      int d0 = degs[idx], d1 = degs[SH + idx];
      int d2 = degs[2 * SH + idx], d3 = degs[3 * SH + idx];
      int dg = d0 + d1 + d2 + d3;
      deg[idx] = dg;
      offsets[idx] = run;
      curs[idx] = run;
      curs[SH + idx] = run + d0;
      curs[2 * SH + idx] = run + d0 + d1;
      curs[3 * SH + idx] = run + d0 + d1 + d2;
      run += dg;
    }
  }
}

// ---- Phase 3: bucket edges by head, sharded cursors ----
__global__ __launch_bounds__(256) void k_scatter(const int4* __restrict__ dkg4,
                                                 int* __restrict__ curs,
                                                 int* __restrict__ bucket) {
  int i = blockIdx.x * 256 + threadIdx.x;
  if (i >= NE / 4) return;
  int4 A = dkg4[3 * i], B = dkg4[3 * i + 1], C = dkg4[3 * i + 2];
  int s = (threadIdx.x & 3) * SH;
  int e = 4 * i;
  bucket[atomicAdd(&curs[s + A.x], 1)] = e;
  bucket[atomicAdd(&curs[s + A.w], 1)] = e + 1;
  bucket[atomicAdd(&curs[s + B.z], 1)] = e + 2;
  bucket[atomicAdd(&curs[s + C.y], 1)] = e + 3;
}

// ---- Phase 4: per-drug top-16 selection, ONE WAVE PER DRUG ----
// Key ((rb>>9)<<32)|e reproduces stable lexsort order exactly.
// Lanes hold <=4 keys (deg<=256), local sort-4, then 16 rounds of
// wave-min merge-extract. Selection is set-valued: any order OK for deg>=16;
// extraction order is ascending anyway (needed for the deg<16 extras path).
#define SELKEY(e) ((((u64)(rbits32(k1x, k1y, (u32)(e)) >> 9)) << 32) | (u32)(e))
#define CSWAP(x, y) { u64 lo_ = x < y ? x : y; u64 hi_ = x < y ? y : x; x = lo_; y = hi_; }
__global__ __launch_bounds__(256) void k_select(const int* __restrict__ bucket,
                                                const int* __restrict__ deg,
                                                const int* __restrict__ offsets,
                                                int* __restrict__ sel,
                                                u32 k1x, u32 k1y,
                                                u32 khx, u32 khy,
                                                u32 klx, u32 kly) {
  __shared__ int asel[4][16];
  int tid = threadIdx.x, lane = tid & 63, wv = tid >> 6;
  int d = blockIdx.x * 4 + wv;
  if (d >= NDRUGS) return;
  int dg = deg[d], off = offsets[d];
  if (dg <= 0) {
    if (lane < 16) sel[d * SSIZE + lane] = -1;
    return;
  }
  if (dg <= 256) {
    u64 a0 = U64MAX, a1 = U64MAX, a2 = U64MAX, a3 = U64MAX;
    if (lane < dg)       a0 = SELKEY(bucket[off + lane]);
    if (lane + 64 < dg)  a1 = SELKEY(bucket[off + lane + 64]);
    if (lane + 128 < dg) a2 = SELKEY(bucket[off + lane + 128]);
    if (lane + 192 < dg) a3 = SELKEY(bucket[off + lane + 192]);
    CSWAP(a0, a1) CSWAP(a2, a3) CSWAP(a0, a2) CSWAP(a1, a3) CSWAP(a1, a2)
    int h = 0;
    if (dg >= SSIZE) {
      u32 myout = 0;
#pragma unroll
      for (int r = 0; r < SSIZE; r++) {
        u64 ex = (h == 0) ? a0 : (h == 1) ? a1 : (h == 2) ? a2 : (h == 3) ? a3 : U64MAX;
        u64 g = ex;
#pragma unroll
        for (int m = 1; m < 64; m <<= 1) {
          u64 o = __shfl_xor(g, m, 64);
          g = o < g ? o : g;
        }
        if (lane == r) myout = (u32)g;
        if (ex == g) h++;
      }
      if (lane < 16) sel[d * SSIZE + lane] = (int)myout;
    } else {
      for (int r = 0; r < dg; r++) {
        u64 ex = (h == 0) ? a0 : (h == 1) ? a1 : (h == 2) ? a2 : (h == 3) ? a3 : U64MAX;
        u64 g = ex;
#pragma unroll
        for (int m = 1; m < 64; m <<= 1) {
          u64 o = __shfl_xor(g, m, 64);
          g = o < g ? o : g;
        }
        if (lane == 0) asel[wv][r] = (int)(u32)g;
        if (ex == g) h++;
      }
      if (lane < dg) sel[d * SSIZE + lane] = asel[wv][lane];
      int need = SSIZE - dg;
      const u32 span = 0x7fffffffu;            // 2^31-1; 2^32 % span = 2
      if (lane < need) {
        u32 j = (u32)(d * SSIZE + lane);
        u32 hi = rbits32(khx, khy, j) % span;
        u32 lo = rbits32(klx, kly, j) % span;
        u32 u = (hi * 2u + lo) % span;         // uint32 wraparound: JAX-exact
        int idx = (int)(u % (u32)dg);
        sel[d * SSIZE + dg + lane] = asel[wv][idx];
      }
    }
  } else if (lane == 0) {                      // deg > 256: serial fallback
    u64 hp[16]; u64 mx = 0; int mi = 0;
    for (int s = 0; s < SSIZE; s++) {
      u64 k = SELKEY(bucket[off + s]);
      hp[s] = k;
      if (k > mx) { mx = k; mi = s; }
    }
    for (int p = SSIZE; p < dg; p++) {
      u64 k = SELKEY(bucket[off + p]);
      if (k < mx) {
        hp[mi] = k; mx = 0;
        for (int s = 0; s < SSIZE; s++)
          if (hp[s] > mx) { mx = hp[s]; mi = s; }
      }
    }
    for (int s = 0; s < SSIZE; s++) sel[d * SSIZE + s] = (int)(u32)hp[s];
  }
}

// ---- Phase 5: edge-MLP + neighbor gather via MFMA (2 drugs/wave) ----
// h(16x64) = V(16x64) @ W1(64x64) + b1, V = dr*rel per edge; exact hi/lo bf16
// split of V (products of two bf16s have 16-bit mantissas -> error-free).
// score(e) = sigma(h[e]) . w2rowsum + sum(b2); neigh = sum score*tail.
__global__ __launch_bounds__(256, 2) void k_gather(const int* __restrict__ sel,
                                                   const int* __restrict__ dkg,
                                                   const float* __restrict__ drug,
                                                   const float* __restrict__ rel,
                                                   const float* __restrict__ tail,
                                                   const float* __restrict__ W1,
                                                   const float* __restrict__ b1,
                                                   const float* __restrict__ W2,
                                                   const float* __restrict__ b2,
                                                   float* __restrict__ neigh) {
  __shared__ __align__(16) u16 Vh[4][16][72];   // stride 144 B: even banks
  __shared__ __align__(16) u16 Vl[4][16][72];
  __shared__ float rs[64];
  int tid = threadIdx.x, lane = tid & 63, wv = tid >> 6;
  int quad = lane >> 4, c = lane & 15;

  if (tid < 64) {                               // W2 row-sums (deterministic)
    float s = 0.f;
    for (int k = 0; k < 64; k++) s += q16(W2[tid * 64 + k]);
    rs[tid] = s;
  }
  __syncthreads();

  // B-fragments of W1 (bf16, exact): B[k=quad*8+jj][n=t*16+c]
  bf16x8 bw[4][2];
#pragma unroll
  for (int t = 0; t < 4; t++)
#pragma unroll
    for (int s = 0; s < 2; s++) {
      union { short h[8]; bf16x8 v; } u;
#pragma unroll
      for (int jj = 0; jj < 8; jj++)
        u.h[jj] = (short)rne16(W1[(s * 32 + quad * 8 + jj) * 64 + t * 16 + c]);
      bw[t][s] = u.v;
    }
  float b1t[4], w2t[4];
#pragma unroll
  for (int t = 0; t < 4; t++) {
    b1t[t] = q16(b1[t * 16 + c]);
    w2t[t] = rs[t * 16 + c];
  }
  float sb2 = q16(b2[lane]);
#pragma unroll
  for (int m = 32; m; m >>= 1) sb2 += __shfl_xor(sb2, m, 64);

  int d0 = (blockIdx.x * 4 + wv) * 2;
  int sv = -1, rlv = 0, tlv = 0;
  if (lane < 32) sv = sel[d0 * SSIZE + lane];
  int es = sv < 0 ? 0 : sv;
  if (lane < 32) { rlv = dkg[3 * es + 2]; tlv = dkg[3 * es + 1]; }

#pragma unroll 1
  for (int dd = 0; dd < 2; dd++) {
    int d = d0 + dd;
    float dr = q16(drug[d * 64 + lane]);
    // Build V (hi/lo): lane = dim j, loop edges
#pragma unroll
    for (int e = 0; e < 16; e++) {
      int rl = __shfl(rlv, dd * 16 + e, 64);
      float v = dr * q16(rel[rl * 64 + lane]);
      u16 hb = rne16(v);
      float lo = v - bfbits2f(hb);
      Vh[wv][e][lane] = hb;
      Vl[wv][e][lane] = rne16(lo);              // exact (<=8-bit mantissa left)
    }
    // A-fragments: row m=c (edge), k-chunk quad*8
    bf16x8 ah[2], al[2];
#pragma unroll
    for (int s = 0; s < 2; s++) {
      ah[s] = *(const bf16x8*)&Vh[wv][c][s * 32 + quad * 8];
      al[s] = *(const bf16x8*)&Vl[wv][c][s * 32 + quad * 8];
    }
    f32x4 acc[4];
#pragma unroll
    for (int t = 0; t < 4; t++) {
      acc[t] = (f32x4){b1t[t], b1t[t], b1t[t], b1t[t]};
#pragma unroll
      for (int s = 0; s < 2; s++) {
        acc[t] = __builtin_amdgcn_mfma_f32_16x16x32_bf16(ah[s], bw[t][s], acc[t], 0, 0, 0);
        acc[t] = __builtin_amdgcn_mfma_f32_16x16x32_bf16(al[s], bw[t][s], acc[t], 0, 0, 0);
      }
    }
    // score rows: sigma, weight by w2rs, reduce over cols (xor within quad)
    float p[4] = {0.f, 0.f, 0.f, 0.f};
#pragma unroll
    for (int t = 0; t < 4; t++)
#pragma unroll
      for (int r = 0; r < 4; r++)
        p[r] = fmaf(1.f / (1.f + __expf(-acc[t][r])), w2t[t], p[r]);
#pragma unroll
    for (int m = 1; m < 16; m <<= 1) {
#pragma unroll
      for (int r = 0; r < 4; r++) p[r] += __shfl_xor(p[r], m, 64);
    }
#pragma unroll
    for (int r = 0; r < 4; r++) p[r] += sb2;
    // tail accumulation, 4 independent chains
    float a0 = 0.f, a1 = 0.f, a2 = 0.f, a3 = 0.f;
#pragma unroll
    for (int e = 0; e < 16; e += 4) {
#pragma unroll
      for (int k = 0; k < 4; k++) {
        int sl = dd * 16 + e + k;
        int ee = __shfl(sv, sl, 64);
        int tl = __shfl(tlv, sl, 64);
        float sc = __shfl(p[(e + k) & 3], ((e + k) >> 2) << 4, 64);
        float tv = q16(tail[tl * 64 + lane]);
        if (ee >= 0) {
          if (k == 0) a0 = fmaf(sc, tv, a0);
          else if (k == 1) a1 = fmaf(sc, tv, a1);
          else if (k == 2) a2 = fmaf(sc, tv, a2);
          else a3 = fmaf(sc, tv, a3);
        }
      }
    }
    neigh[d * 64 + lane] = (a0 + a1) + (a2 + a3);
  }
}

// ---- Phase 5b: y = [drug | neigh] @ Wc + bc via MFMA (16 drugs/wave) ----
// drug cols are exact bf16; neigh cols use hi/lo split (residual ~2^-17 rel).
__global__ __launch_bounds__(256, 2) void k_epi(const float* __restrict__ drug,
                                                const float* __restrict__ neigh,
                                                const float* __restrict__ Wc,
                                                const float* __restrict__ bc,
                                                float* __restrict__ y) {
  __shared__ __align__(16) u16 Ah[4][16][136];  // hi bits, K=128
  __shared__ __align__(16) u16 Al[4][16][72];   // lo bits, K=64..127
  int tid = threadIdx.x, lane = tid & 63, wv = tid >> 6;
  int quad = lane >> 4, c = lane & 15;

  bf16x8 bw[4][4];
#pragma unroll
  for (int t = 0; t < 4; t++)
#pragma unroll
    for (int s = 0; s < 4; s++) {
      union { short h[8]; bf16x8 v; } u;
#pragma unroll
      for (int jj = 0; jj < 8; jj++)
        u.h[jj] = (short)rne16(Wc[(s * 32 + quad * 8 + jj) * 64 + t * 16 + c]);
      bw[t][s] = u.v;
    }
  float bct[4];
#pragma unroll
  for (int t = 0; t < 4; t++) bct[t] = q16(bc[t * 16 + c]);

  int D0 = (blockIdx.x * 4 + wv) * 16;
#pragma unroll 1
  for (int rr = 0; rr < 16; rr++) {
    int d = D0 + rr;
    int dsafe = d < NDRUGS ? d : NDRUGS - 1;
    float dv = q16(drug[dsafe * 64 + lane]);
    Ah[wv][rr][lane] = rne16(dv);               // exact
    float nv = neigh[dsafe * 64 + lane];
    u16 nh = rne16(nv);
    Ah[wv][rr][64 + lane] = nh;
    Al[wv][rr][lane] = rne16(nv - bfbits2f(nh));
  }
  f32x4 acc[4];
#pragma unroll
  for (int t = 0; t < 4; t++) acc[t] = (f32x4){bct[t], bct[t], bct[t], bct[t]};
#pragma unroll
  for (int s = 0; s < 4; s++) {
    bf16x8 a = *(const bf16x8*)&Ah[wv][c][s * 32 + quad * 8];
#pragma unroll
    for (int t = 0; t < 4; t++)
      acc[t] = __builtin_amdgcn_mfma_f32_16x16x32_bf16(a, bw[t][s], acc[t], 0, 0, 0);
  }
#pragma unroll
  for (int s = 0; s < 2; s++) {
    bf16x8 a = *(const bf16x8*)&Al[wv][c][s * 32 + quad * 8];
#pragma unroll
    for (int t = 0; t < 4; t++)
      acc[t] = __builtin_amdgcn_mfma_f32_16x16x32_bf16(a, bw[t][2 + s], acc[t], 0, 0, 0);
  }
#pragma unroll
  for (int t = 0; t < 4; t++)
#pragma unroll
    for (int r = 0; r < 4; r++) {
      int row = D0 + quad * 4 + r;
      if (row < NDRUGS) y[row * 64 + t * 16 + c] = acc[t][r];
    }
}

// ---- Phase 6a: coalesced per-block column partial sums ----
__global__ __launch_bounds__(256) void k_stats1(const float* __restrict__ y,
                                                float* __restrict__ ps,
                                                float* __restrict__ pq) {
  __shared__ float S[4][64], Q[4][64];
  int b = blockIdx.x;
  int tid = threadIdx.x, c = tid & 63, rsub = tid >> 6;
  float s = 0.f, q = 0.f;
  int r0 = b * 100;
  for (int rr = rsub; rr < 100; rr += 4) {
    float v = y[(r0 + rr) * 64 + c];
    s += v;
    q = fmaf(v, v, q);
  }
  S[rsub][c] = s; Q[rsub][c] = q;
  __syncthreads();
  if (tid < 64) {
    s = S[0][tid] + S[1][tid] + S[2][tid] + S[3][tid];
    q = Q[0][tid] + Q[1][tid] + Q[2][tid] + Q[3][tid];
    ps[b * 64 + tid] = s;
    pq[b * 64 + tid] = q;
  }
}

// ---- Phase 6b: finalize mean / inv-std ----
__global__ __launch_bounds__(64) void k_stats2(const float* __restrict__ ps,
                                               const float* __restrict__ pq,
                                               float* __restrict__ stats) {
  int c = threadIdx.x;
  float s = 0.f, q = 0.f;
  for (int b = 0; b < 100; b++) { s += ps[b * 64 + c]; q += pq[b * 64 + c]; }
  float mean = s / (float)NDRUGS;
  float var = q / (float)NDRUGS - mean * mean;
  stats[c] = mean;
  stats[64 + c] = rsqrtf(var + 1e-5f);
}

// ---- Phase 7: BN (in place) + passthrough copies, float4 ----
__global__ __launch_bounds__(256) void k_final(const float4* __restrict__ HFE4,
                                               const float4* __restrict__ Xv4,
                                               const float* __restrict__ gamma,
                                               const float* __restrict__ beta,
                                               const float* __restrict__ stats,
                                               float4* __restrict__ out4) {
  int i4 = blockIdx.x * 256 + threadIdx.x;
  if (i4 < 160000) {
    float4 a = HFE4[i4];
    a.x = q16(a.x); a.y = q16(a.y); a.z = q16(a.z); a.w = q16(a.w);
    out4[i4] = a;
  } else if (i4 < 320000) {
    int idx4 = i4 - 160000;
    int j0 = (idx4 * 4) & 63;
    float4 v = out4[i4];                      // y, in place
    float4 r;
    r.x = q16(fmaf(q16(gamma[j0+0]) * (v.x - stats[j0+0]), stats[64+j0+0], q16(beta[j0+0])));
    r.y = q16(fmaf(q16(gamma[j0+1]) * (v.y - stats[j0+1]), stats[64+j0+1], q16(beta[j0+1])));
    r.z = q16(fmaf(q16(gamma[j0+2]) * (v.z - stats[j0+2]), stats[64+j0+2], q16(beta[j0+2])));
    r.w = q16(fmaf(q16(gamma[j0+3]) * (v.w - stats[j0+3]), stats[64+j0+3], q16(beta[j0+3])));
    out4[i4] = r;
  } else if (i4 < 322500) {
    float4 a = Xv4[i4 - 320000];
    a.x = q16(a.x); a.y = q16(a.y); a.z = q16(a.z); a.w = q16(a.w);
    out4[i4] = a;
  }
}

extern "C" void kernel_launch(void* const* d_in, const int* in_sizes, int n_in,
                              void* d_out, int out_size, void* d_ws, size_t ws_size,
                              hipStream_t stream) {
  const float* drug = (const float*)d_in[2];
  const float* rel  = (const float*)d_in[3];
  const float* tail = (const float*)d_in[4];
  const float* W1   = (const float*)d_in[5];
  const float* b1   = (const float*)d_in[6];
  const float* W2   = (const float*)d_in[7];
  const float* b2   = (const float*)d_in[8];
  const float* Wc   = (const float*)d_in[9];
  const float* bc   = (const float*)d_in[10];
  const float* gam  = (const float*)d_in[11];
  const float* bet  = (const float*)d_in[12];
  const int*   dkg  = (const int*)d_in[13];
  float* out = (float*)d_out;
  float* y = out + 640000;                   // Output-1 region doubles as y

  // ---- Workspace (footprint <= 4,760,512 B, proven safe R4-R6) ----
  char* w = (char*)d_ws;
  int*   bucket = (int*)(w);                 // E ints; dead after k_select
  float* neigh  = (float*)(w);               // 2.56 MB, overlays dead bucket
  float* ps     = (float*)(w + 2600000);     // 25.6 KB (still inside bucket)
  float* pq     = (float*)(w + 2630000);     // 25.6 KB
  int*   degs   = (int*)(w + 4000000);       // 4 x SH shard histograms
  int*   curs   = (int*)(w + 4163840);       // 4 x SH shard cursors
  int*   sel    = (int*)(w + 4000000);       // overlays degs/curs after scatter
  int*   deg    = (int*)(w + 4640000);       // 10,000
  int*   offs   = (int*)(w + 4720000);       // 10,000
  float* stats  = (float*)(w + 4760000);     // 128

  // Threefry key derivation (seed 42, partitionable split semantics)
  u32 k1x, k1y, k2x, k2y, khx, khy, klx, kly;
  tf2x32(0u, 42u, 0u, 0u, k1x, k1y);   // split(key)[0] -> uniform r
  tf2x32(0u, 42u, 0u, 1u, k2x, k2y);   // split(key)[1] -> randint key
  tf2x32(k2x, k2y, 0u, 0u, khx, khy);  // split(k2)[0] -> higher_bits
  tf2x32(k2x, k2y, 0u, 1u, klx, kly);  // split(k2)[1] -> lower_bits

  hipMemsetAsync(degs, 0, 4 * SH * sizeof(int), stream);
  k_hist<<<(NE / 4 + 255) / 256, 256, 0, stream>>>((const int4*)dkg, degs);
  k_scan<<<1, 1024, 0, stream>>>(degs, deg, offs, curs);
  k_scatter<<<(NE / 4 + 255) / 256, 256, 0, stream>>>((const int4*)dkg, curs,
                                                      bucket);
  k_select<<<2500, 256, 0, stream>>>(bucket, deg, offs, sel,
                                     k1x, k1y, khx, khy, klx, kly);
  k_gather<<<1250, 256, 0, stream>>>(sel, dkg, drug, rel, tail,
                                     W1, b1, W2, b2, neigh);
  k_epi<<<157, 256, 0, stream>>>(drug, neigh, Wc, bc, y);
  k_stats1<<<100, 256, 0, stream>>>(y, ps, pq);
  k_stats2<<<1, 64, 0, stream>>>(ps, pq, stats);
  k_final<<<(322500 + 255) / 256, 256, 0, stream>>>((const float4*)d_in[0],
                                                    (const float4*)d_in[1],
                                                    gam, bet, stats,
                                                    (float4*)out);
}

// Round 8
// 255.724 us; speedup vs baseline: 2.1171x; 1.2173x over previous
//
#include <hip/hip_runtime.h>
#include <stdint.h>

// ---- Problem constants ----
#define NDRUGS 10000
#define NTAILS 20000
#define NE     1000000
#define SSIZE  16
#define SH     10240        // shard stride (ints) for deg shards
#define CSLOT  96           // candidate slots per drug

typedef unsigned int  u32;
typedef unsigned short u16;
typedef unsigned long long u64;
typedef __attribute__((ext_vector_type(8))) short bf16x8;
typedef __attribute__((ext_vector_type(4))) float f32x4;
#define U64MAX 0xffffffffffffffffULL

// ---- Threefry-2x32-20 (exact JAX semantics) ----
__host__ __device__ __forceinline__ void tf2x32(u32 k0, u32 k1, u32 x0, u32 x1,
                                                u32& o0, u32& o1) {
  u32 ks2 = k0 ^ k1 ^ 0x1BD11BDAu;
  x0 += k0; x1 += k1;
#define TFR(r) { x0 += x1; x1 = (x1 << r) | (x1 >> (32 - r)); x1 ^= x0; }
  TFR(13) TFR(15) TFR(26) TFR(6)
  x0 += k1; x1 += ks2 + 1u;
  TFR(17) TFR(29) TFR(16) TFR(24)
  x0 += ks2; x1 += k0 + 2u;
  TFR(13) TFR(15) TFR(26) TFR(6)
  x0 += k0; x1 += k1 + 3u;
  TFR(17) TFR(29) TFR(16) TFR(24)
  x0 += k1; x1 += ks2 + 4u;
  TFR(13) TFR(15) TFR(26) TFR(6)
  x0 += ks2; x1 += k0 + 5u;
#undef TFR
  o0 = x0; o1 = x1;
}

__device__ __forceinline__ u32 rbits32(u32 kx, u32 ky, u32 i) {
  u32 o0, o1;
  tf2x32(kx, ky, 0u, i, o0, o1);
  return o0 ^ o1;   // partitionable fold
}
// Stable-lexsort-equivalent composite key
#define SELKEY(e) ((((u64)(rbits32(k1x, k1y, (u32)(e)) >> 9)) << 32) | (u32)(e))
#define CSWAP(x, y) { u64 lo_ = x < y ? x : y; u64 hi_ = x < y ? y : x; x = lo_; y = hi_; }

// ---- bf16 helpers (RNE, matches np/jax bf16 cast) ----
__device__ __forceinline__ float q16(float f) {
  u32 x = __builtin_bit_cast(u32, f);
  u32 lsb = (x >> 16) & 1u;
  x = (x + 0x7fffu + lsb) & 0xffff0000u;
  return __builtin_bit_cast(float, x);
}
__device__ __forceinline__ u16 rne16(float f) {
  u32 x = __builtin_bit_cast(u32, f);
  u32 lsb = (x >> 16) & 1u;
  return (u16)((x + 0x7fffu + lsb) >> 16);
}
__device__ __forceinline__ float bfbits2f(u16 b) {
  u32 x = ((u32)b) << 16;
  return __builtin_bit_cast(float, x);
}

// ---- Phase 1: degree histogram, 4-way sharded counters ----
__global__ __launch_bounds__(256) void k_hist(const int4* __restrict__ dkg4,
                                              int* __restrict__ degs) {
  int i = blockIdx.x * 256 + threadIdx.x;
  if (i >= NE / 4) return;
  int4 A = dkg4[3 * i], B = dkg4[3 * i + 1], C = dkg4[3 * i + 2];
  int s = (threadIdx.x & 3) * SH;
  atomicAdd(&degs[s + A.x], 1);
  atomicAdd(&degs[s + A.w], 1);
  atomicAdd(&degs[s + B.z], 1);
  atomicAdd(&degs[s + C.y], 1);
}

// ---- Phase 2: merge deg shards; per-drug candidate threshold; init cnt/nflag.
// thr guarantees: deg<=40 -> pass-all (exact, covers deg<16 extras);
// else mean ~48 candidates. c>=16 => candidates contain the exact top-16.
__global__ __launch_bounds__(256) void k_thr(const int* __restrict__ degs,
                                             int* __restrict__ deg,
                                             u32* __restrict__ thr,
                                             int* __restrict__ cnt,
                                             int* __restrict__ nflag) {
  int d = blockIdx.x * 256 + threadIdx.x;
  if (d == 0) *nflag = 0;
  if (d >= NDRUGS) return;
  int dg = degs[d] + degs[SH + d] + degs[2 * SH + d] + degs[3 * SH + d];
  deg[d] = dg;
  cnt[d] = 0;
  thr[d] = (dg <= 40) ? 0x800000u
                      : (402653184u + (u32)dg - 1u) / (u32)dg;  // ceil(48*2^23/dg)
}

// ---- Phase 3: candidate emission (XCD-sliced; replaces CSR scatter) ----
// 8 slices x 125 blocks; slice = blockIdx&7 handles drugs [s*1250,(s+1)*1250).
// Writes confined to per-slice 480 KB -> single-XCD L2 locality.
__global__ __launch_bounds__(256) void k_cand(const int* __restrict__ dkg,
                                              const u32* __restrict__ thr,
                                              int* __restrict__ cnt,
                                              int* __restrict__ cand,
                                              int* __restrict__ nflag,
                                              int* __restrict__ flaglist,
                                              u32 k1x, u32 k1y) {
  __shared__ u32 thr_l[1250];
  int slice = blockIdx.x & 7, bs = blockIdx.x >> 3;
  int sbase = slice * 1250;
  for (int j = threadIdx.x; j < 1250; j += 256) thr_l[j] = thr[sbase + j];
  __syncthreads();
  int base4 = bs * 2000;
#pragma unroll 1
  for (int it = 0; it < 8; it++) {
    int idx = it * 256 + threadIdx.x;
    if (idx >= 2000) break;
    int i4 = base4 + idx;
    int h[4];
    h[0] = dkg[12 * i4];     h[1] = dkg[12 * i4 + 3];
    h[2] = dkg[12 * i4 + 6]; h[3] = dkg[12 * i4 + 9];
#pragma unroll
    for (int k = 0; k < 4; k++) {
      u32 rh = (u32)(h[k] - sbase);
      if (rh < 1250u) {
        int e = 4 * i4 + k;
        u32 rb = rbits32(k1x, k1y, (u32)e);
        if ((rb >> 9) < thr_l[rh]) {
          int pos = atomicAdd(&cnt[h[k]], 1);
          if (pos < CSLOT) cand[h[k] * CSLOT + pos] = e;
          else if (pos == CSLOT) {
            int ix = atomicAdd(nflag, 1);
            if (ix < 256) flaglist[ix] = h[k];
          }
        }
      }
    }
  }
}

// ---- Phase 4: wave-per-drug top-16 from candidates ----
__global__ __launch_bounds__(256) void k_select(const int* __restrict__ cand,
                                                const int* __restrict__ cnt,
                                                const int* __restrict__ deg,
                                                int* __restrict__ sel,
                                                int* __restrict__ nflag,
                                                int* __restrict__ flaglist,
                                                u32 k1x, u32 k1y,
                                                u32 khx, u32 khy,
                                                u32 klx, u32 kly) {
  __shared__ int asel[4][16];
  int tid = threadIdx.x, lane = tid & 63, wv = tid >> 6;
  int d = blockIdx.x * 4 + wv;
  if (d >= NDRUGS) return;
  int dg = deg[d], n = cnt[d], off = d * CSLOT;
  if (dg <= 0) {
    if (lane < 16) sel[d * SSIZE + lane] = -1;
    return;
  }
  if (dg >= SSIZE) {
    if (n < SSIZE || n > CSLOT) {          // filter failed -> exact fallback
      if (lane == 0) {
        int ix = atomicAdd(nflag, 1);
        if (ix < 256) flaglist[ix] = d;
      }
      return;
    }
    u64 a0 = U64MAX, a1 = U64MAX;
    if (lane < n)      a0 = SELKEY(cand[off + lane]);
    if (lane + 64 < n) a1 = SELKEY(cand[off + lane + 64]);
    CSWAP(a0, a1)
    int h = 0; u32 my = 0;
#pragma unroll
    for (int r = 0; r < SSIZE; r++) {
      u64 ex = (h == 0) ? a0 : (h == 1) ? a1 : U64MAX;
      u64 g = ex;
#pragma unroll
      for (int m = 1; m < 64; m <<= 1) {
        u64 o = __shfl_xor(g, m, 64);
        g = o < g ? o : g;
      }
      if (lane == r) my = (u32)g;
      if (ex == g) h++;
    }
    if (lane < 16) sel[d * SSIZE + lane] = (int)my;
  } else {
    // deg<16: thr passed all -> n == dg; ascending extraction + extras
    u64 a0 = (lane < n) ? SELKEY(cand[off + lane]) : U64MAX;
    int h = 0;
    for (int r = 0; r < n; r++) {
      u64 ex = (h == 0) ? a0 : U64MAX;
      u64 g = ex;
#pragma unroll
      for (int m = 1; m < 64; m <<= 1) {
        u64 o = __shfl_xor(g, m, 64);
        g = o < g ? o : g;
      }
      if (lane == 0) asel[wv][r] = (int)(u32)g;
      if (ex == g) h++;
    }
    if (lane < n) sel[d * SSIZE + lane] = asel[wv][lane];
    int need = SSIZE - n;
    const u32 span = 0x7fffffffu;           // 2^31-1; 2^32 % span = 2
    if (lane < need) {
      u32 j = (u32)(d * SSIZE + lane);
      u32 hi = rbits32(khx, khy, j) % span;
      u32 lo = rbits32(klx, kly, j) % span;
      u32 u = (hi * 2u + lo) % span;        // uint32 wraparound: JAX-exact
      int idx = (int)(u % (u32)n);
      sel[d * SSIZE + n + lane] = asel[wv][idx];
    }
  }
}

// ---- Phase 4b: exact fallback for flagged drugs (normally: load, exit) ----
__global__ __launch_bounds__(256) void k_fix(const int* __restrict__ dkg,
                                             const int* __restrict__ nflag,
                                             const int* __restrict__ flaglist,
                                             int* __restrict__ sel,
                                             u32 k1x, u32 k1y) {
  int nf = *nflag;
  if (nf <= 0) return;
  if (nf > 256) nf = 256;
  __shared__ u64 pool[256 * 16];
  int tid = threadIdx.x;
  for (int f = 0; f < nf; f++) {
    int d = flaglist[f];
    u64 loc[16];
#pragma unroll
    for (int i = 0; i < 16; i++) loc[i] = U64MAX;
    u64 mx = U64MAX; int mi = 0;
    for (int e = tid; e < NE; e += 256) {
      if (dkg[3 * e] == d) {
        u64 k = SELKEY(e);
        if (k < mx) {
          loc[mi] = k; mx = 0;
          for (int i = 0; i < 16; i++)
            if (loc[i] > mx) { mx = loc[i]; mi = i; }
        }
      }
    }
#pragma unroll
    for (int i = 0; i < 16; i++) pool[tid * 16 + i] = loc[i];
    __syncthreads();
    if (tid == 0) {
      u64 best[16];
#pragma unroll
      for (int i = 0; i < 16; i++) best[i] = U64MAX;
      u64 bm = U64MAX; int bi = 0;
      for (int i = 0; i < 256 * 16; i++) {
        u64 k = pool[i];
        if (k < bm) {
          best[bi] = k; bm = 0;
          for (int j = 0; j < 16; j++)
            if (best[j] > bm) { bm = best[j]; bi = j; }
        }
      }
      for (int s = 0; s < 16; s++) sel[d * SSIZE + s] = (int)(u32)best[s];
    }
    __syncthreads();
  }
}

// ---- Phase 5: edge-MLP + neighbor gather via MFMA (2 drugs/wave) ----
__global__ __launch_bounds__(256, 2) void k_gather(const int* __restrict__ sel,
                                                   const int* __restrict__ dkg,
                                                   const float* __restrict__ drug,
                                                   const float* __restrict__ rel,
                                                   const float* __restrict__ tail,
                                                   const float* __restrict__ W1,
                                                   const float* __restrict__ b1,
                                                   const float* __restrict__ W2,
                                                   const float* __restrict__ b2,
                                                   float* __restrict__ neigh,
                                                   float* __restrict__ psq) {
  __shared__ __align__(16) u16 Vh[4][16][72];
  __shared__ __align__(16) u16 Vl[4][16][72];
  __shared__ float rs[64];
  int tid = threadIdx.x, lane = tid & 63, wv = tid >> 6;
  int quad = lane >> 4, c = lane & 15;

  if (blockIdx.x == 0 && tid < 128) psq[tid] = 0.f;   // init stats accumulators
  if (tid < 64) {
    float s = 0.f;
    for (int k = 0; k < 64; k++) s += q16(W2[tid * 64 + k]);
    rs[tid] = s;
  }
  __syncthreads();

  bf16x8 bw[4][2];
#pragma unroll
  for (int t = 0; t < 4; t++)
#pragma unroll
    for (int s = 0; s < 2; s++) {
      union { short h[8]; bf16x8 v; } u;
#pragma unroll
      for (int jj = 0; jj < 8; jj++)
        u.h[jj] = (short)rne16(W1[(s * 32 + quad * 8 + jj) * 64 + t * 16 + c]);
      bw[t][s] = u.v;
    }
  float b1t[4], w2t[4];
#pragma unroll
  for (int t = 0; t < 4; t++) {
    b1t[t] = q16(b1[t * 16 + c]);
    w2t[t] = rs[t * 16 + c];
  }
  float sb2 = q16(b2[lane]);
#pragma unroll
  for (int m = 32; m; m >>= 1) sb2 += __shfl_xor(sb2, m, 64);

  int d0 = (blockIdx.x * 4 + wv) * 2;
  int sv = -1, rlv = 0, tlv = 0;
  if (lane < 32) sv = sel[d0 * SSIZE + lane];
  int es = sv < 0 ? 0 : sv;
  if (lane < 32) { rlv = dkg[3 * es + 2]; tlv = dkg[3 * es + 1]; }

#pragma unroll 1
  for (int dd = 0; dd < 2; dd++) {
    int d = d0 + dd;
    float dr = q16(drug[d * 64 + lane]);
#pragma unroll
    for (int e = 0; e < 16; e++) {
      int rl = __shfl(rlv, dd * 16 + e, 64);
      float v = dr * q16(rel[rl * 64 + lane]);
      u16 hb = rne16(v);
      float lo = v - bfbits2f(hb);
      Vh[wv][e][lane] = hb;
      Vl[wv][e][lane] = rne16(lo);          // exact split
    }
    bf16x8 ah[2], al[2];
#pragma unroll
    for (int s = 0; s < 2; s++) {
      ah[s] = *(const bf16x8*)&Vh[wv][c][s * 32 + quad * 8];
      al[s] = *(const bf16x8*)&Vl[wv][c][s * 32 + quad * 8];
    }
    f32x4 acc[4];
#pragma unroll
    for (int t = 0; t < 4; t++) {
      acc[t] = (f32x4){b1t[t], b1t[t], b1t[t], b1t[t]};
#pragma unroll
      for (int s = 0; s < 2; s++) {
        acc[t] = __builtin_amdgcn_mfma_f32_16x16x32_bf16(ah[s], bw[t][s], acc[t], 0, 0, 0);
        acc[t] = __builtin_amdgcn_mfma_f32_16x16x32_bf16(al[s], bw[t][s], acc[t], 0, 0, 0);
      }
    }
    float p[4] = {0.f, 0.f, 0.f, 0.f};
#pragma unroll
    for (int t = 0; t < 4; t++)
#pragma unroll
      for (int r = 0; r < 4; r++)
        p[r] = fmaf(1.f / (1.f + __expf(-acc[t][r])), w2t[t], p[r]);
#pragma unroll
    for (int m = 1; m < 16; m <<= 1) {
#pragma unroll
      for (int r = 0; r < 4; r++) p[r] += __shfl_xor(p[r], m, 64);
    }
#pragma unroll
    for (int r = 0; r < 4; r++) p[r] += sb2;
    float a0 = 0.f, a1 = 0.f, a2 = 0.f, a3 = 0.f;
#pragma unroll
    for (int e = 0; e < 16; e += 4) {
#pragma unroll
      for (int k = 0; k < 4; k++) {
        int sl = dd * 16 + e + k;
        int ee = __shfl(sv, sl, 64);
        int tl = __shfl(tlv, sl, 64);
        float sc = __shfl(p[(e + k) & 3], ((e + k) >> 2) << 4, 64);
        float tv = q16(tail[tl * 64 + lane]);
        if (ee >= 0) {
          if (k == 0) a0 = fmaf(sc, tv, a0);
          else if (k == 1) a1 = fmaf(sc, tv, a1);
          else if (k == 2) a2 = fmaf(sc, tv, a2);
          else a3 = fmaf(sc, tv, a3);
        }
      }
    }
    neigh[d * 64 + lane] = (a0 + a1) + (a2 + a3);
  }
}

// ---- Phase 5b: y = [drug | neigh] @ Wc + bc via MFMA (16 drugs/wave) ----
__global__ __launch_bounds__(256, 2) void k_epi(const float* __restrict__ drug,
                                                const float* __restrict__ neigh,
                                                const float* __restrict__ Wc,
                                                const float* __restrict__ bc,
                                                float* __restrict__ y) {
  __shared__ __align__(16) u16 Ah[4][16][136];
  __shared__ __align__(16) u16 Al[4][16][72];
  int tid = threadIdx.x, lane = tid & 63, wv = tid >> 6;
  int quad = lane >> 4, c = lane & 15;

  bf16x8 bw[4][4];
#pragma unroll
  for (int t = 0; t < 4; t++)
#pragma unroll
    for (int s = 0; s < 4; s++) {
      union { short h[8]; bf16x8 v; } u;
#pragma unroll
      for (int jj = 0; jj < 8; jj++)
        u.h[jj] = (short)rne16(Wc[(s * 32 + quad * 8 + jj) * 64 + t * 16 + c]);
      bw[t][s] = u.v;
    }
  float bct[4];
#pragma unroll
  for (int t = 0; t < 4; t++) bct[t] = q16(bc[t * 16 + c]);

  int D0 = (blockIdx.x * 4 + wv) * 16;
#pragma unroll 1
  for (int rr = 0; rr < 16; rr++) {
    int d = D0 + rr;
    int dsafe = d < NDRUGS ? d : NDRUGS - 1;
    float dv = q16(drug[dsafe * 64 + lane]);
    Ah[wv][rr][lane] = rne16(dv);
    float nv = neigh[dsafe * 64 + lane];
    u16 nh = rne16(nv);
    Ah[wv][rr][64 + lane] = nh;
    Al[wv][rr][lane] = rne16(nv - bfbits2f(nh));
  }
  f32x4 acc[4];
#pragma unroll
  for (int t = 0; t < 4; t++) acc[t] = (f32x4){bct[t], bct[t], bct[t], bct[t]};
#pragma unroll
  for (int s = 0; s < 4; s++) {
    bf16x8 a = *(const bf16x8*)&Ah[wv][c][s * 32 + quad * 8];
#pragma unroll
    for (int t = 0; t < 4; t++)
      acc[t] = __builtin_amdgcn_mfma_f32_16x16x32_bf16(a, bw[t][s], acc[t], 0, 0, 0);
  }
#pragma unroll
  for (int s = 0; s < 2; s++) {
    bf16x8 a = *(const bf16x8*)&Al[wv][c][s * 32 + quad * 8];
#pragma unroll
    for (int t = 0; t < 4; t++)
      acc[t] = __builtin_amdgcn_mfma_f32_16x16x32_bf16(a, bw[t][2 + s], acc[t], 0, 0, 0);
  }
#pragma unroll
  for (int t = 0; t < 4; t++)
#pragma unroll
    for (int r = 0; r < 4; r++) {
      int row = D0 + quad * 4 + r;
      if (row < NDRUGS) y[row * 64 + t * 16 + c] = acc[t][r];
    }
}

// ---- Phase 6: per-column sums via atomics into 128 floats ----
__global__ __launch_bounds__(256) void k_stats1(const float* __restrict__ y,
                                                float* __restrict__ ps,
                                                float* __restrict__ pq) {
  __shared__ float S[4][64], Q[4][64];
  int b = blockIdx.x;
  int tid = threadIdx.x, c = tid & 63, rsub = tid >> 6;
  float s = 0.f, q = 0.f;
  int r0 = b * 100;
  for (int rr = rsub; rr < 100; rr += 4) {
    float v = y[(r0 + rr) * 64 + c];
    s += v;
    q = fmaf(v, v, q);
  }
  S[rsub][c] = s; Q[rsub][c] = q;
  __syncthreads();
  if (tid < 64) {
    s = S[0][tid] + S[1][tid] + S[2][tid] + S[3][tid];
    q = Q[0][tid] + Q[1][tid] + Q[2][tid] + Q[3][tid];
    atomicAdd(&ps[tid], s);
    atomicAdd(&pq[tid], q);
  }
}

// ---- Phase 7: BN (stats inline) + passthrough copies, float4 ----
__global__ __launch_bounds__(256) void k_final(const float4* __restrict__ HFE4,
                                               const float4* __restrict__ Xv4,
                                               const float* __restrict__ gamma,
                                               const float* __restrict__ beta,
                                               const float* __restrict__ ps,
                                               const float* __restrict__ pq,
                                               float4* __restrict__ out4) {
  int i4 = blockIdx.x * 256 + threadIdx.x;
  if (i4 < 160000) {
    float4 a = HFE4[i4];
    a.x = q16(a.x); a.y = q16(a.y); a.z = q16(a.z); a.w = q16(a.w);
    out4[i4] = a;
  } else if (i4 < 320000) {
    int idx4 = i4 - 160000;
    int j0 = (idx4 * 4) & 63;
    float4 S = *(const float4*)&ps[j0];
    float4 Q = *(const float4*)&pq[j0];
    float4 v = out4[i4];                      // y, in place
    float4 r;
#define BN1(X, SS, QQ, JJ)                                                 \
    { float m = SS / 10000.f;                                              \
      float inv = rsqrtf(QQ / 10000.f - m * m + 1e-5f);                    \
      r.X = q16(fmaf(q16(gamma[JJ]) * (v.X - m), inv, q16(beta[JJ]))); }
    BN1(x, S.x, Q.x, j0 + 0)
    BN1(y, S.y, Q.y, j0 + 1)
    BN1(z, S.z, Q.z, j0 + 2)
    BN1(w, S.w, Q.w, j0 + 3)
#undef BN1
    out4[i4] = r;
  } else if (i4 < 322500) {
    float4 a = Xv4[i4 - 320000];
    a.x = q16(a.x); a.y = q16(a.y); a.z = q16(a.z); a.w = q16(a.w);
    out4[i4] = a;
  }
}

extern "C" void kernel_launch(void* const* d_in, const int* in_sizes, int n_in,
                              void* d_out, int out_size, void* d_ws, size_t ws_size,
                              hipStream_t stream) {
  const float* drug = (const float*)d_in[2];
  const float* rel  = (const float*)d_in[3];
  const float* tail = (const float*)d_in[4];
  const float* W1   = (const float*)d_in[5];
  const float* b1   = (const float*)d_in[6];
  const float* W2   = (const float*)d_in[7];
  const float* b2   = (const float*)d_in[8];
  const float* Wc   = (const float*)d_in[9];
  const float* bc   = (const float*)d_in[10];
  const float* gam  = (const float*)d_in[11];
  const float* bet  = (const float*)d_in[12];
  const int*   dkg  = (const int*)d_in[13];
  float* out = (float*)d_out;
  float* y = out + 640000;                   // Output-1 region doubles as y

  // ---- Workspace (footprint 4,760,004 B <= proven-safe 4,760,512) ----
  char* w = (char*)d_ws;
  int*   cand   = (int*)(w);                 // 10000*96*4 = 3,840,000; dead after k_fix
  float* neigh  = (float*)(w);               // 2.56 MB, overlays dead cand
  float* ps     = (float*)(w + 2600000);     // 256 B (inside dead cand region)
  float* pq     = (float*)(w + 2600256);     // 256 B
  int*   flagl  = (int*)(w + 3900000);       // 1 KB
  int*   nflag  = (int*)(w + 3904096);       // 4 B
  int*   degs   = (int*)(w + 4000000);       // 4 x SH shards; dead after k_thr
  int*   sel    = (int*)(w + 4000000);       // 640 KB, overlays degs (post-thr)
  int*   cnt    = (int*)(w + 4640000);       // 40 KB
  u32*   thr    = (u32*)(w + 4680000);       // 40 KB
  int*   deg    = (int*)(w + 4720000);       // 40 KB

  // Threefry key derivation (seed 42, partitionable split semantics)
  u32 k1x, k1y, k2x, k2y, khx, khy, klx, kly;
  tf2x32(0u, 42u, 0u, 0u, k1x, k1y);   // split(key)[0] -> uniform r
  tf2x32(0u, 42u, 0u, 1u, k2x, k2y);   // split(key)[1] -> randint key
  tf2x32(k2x, k2y, 0u, 0u, khx, khy);  // split(k2)[0] -> higher_bits
  tf2x32(k2x, k2y, 0u, 1u, klx, kly);  // split(k2)[1] -> lower_bits

  hipMemsetAsync(degs, 0, 4 * SH * sizeof(int), stream);
  k_hist<<<(NE / 4 + 255) / 256, 256, 0, stream>>>((const int4*)dkg, degs);
  k_thr<<<40, 256, 0, stream>>>(degs, deg, thr, cnt, nflag);
  k_cand<<<1000, 256, 0, stream>>>(dkg, thr, cnt, cand, nflag, flagl, k1x, k1y);
  k_select<<<2500, 256, 0, stream>>>(cand, cnt, deg, sel, nflag, flagl,
                                     k1x, k1y, khx, khy, klx, kly);
  k_fix<<<1, 256, 0, stream>>>(dkg, nflag, flagl, sel, k1x, k1y);
  k_gather<<<1250, 256, 0, stream>>>(sel, dkg, drug, rel, tail,
                                     W1, b1, W2, b2, neigh, ps);
  k_epi<<<157, 256, 0, stream>>>(drug, neigh, Wc, bc, y);
  k_stats1<<<100, 256, 0, stream>>>(y, ps, pq);
  k_final<<<(322500 + 255) / 256, 256, 0, stream>>>((const float4*)d_in[0],
                                                    (const float4*)d_in[1],
                                                    gam, bet, ps, pq,
                                                    (float4*)out);
}

// Round 9
// 246.730 us; speedup vs baseline: 2.1943x; 1.0365x over previous
//
#include <hip/hip_runtime.h>
#include <stdint.h>

// ---- Problem constants ----
#define NDRUGS 10000
#define NTAILS 20000
#define NE     1000000
#define SSIZE  16
#define SH     10240        // shard stride (ints) for deg shards
#define CSLOT  96           // candidate slots per drug

typedef unsigned int  u32;
typedef unsigned short u16;
typedef unsigned long long u64;
typedef __attribute__((ext_vector_type(8))) short bf16x8;
typedef __attribute__((ext_vector_type(4))) float f32x4;
#define U64MAX 0xffffffffffffffffULL

// ---- Threefry-2x32-20 (exact JAX semantics) ----
__host__ __device__ __forceinline__ void tf2x32(u32 k0, u32 k1, u32 x0, u32 x1,
                                                u32& o0, u32& o1) {
  u32 ks2 = k0 ^ k1 ^ 0x1BD11BDAu;
  x0 += k0; x1 += k1;
#define TFR(r) { x0 += x1; x1 = (x1 << r) | (x1 >> (32 - r)); x1 ^= x0; }
  TFR(13) TFR(15) TFR(26) TFR(6)
  x0 += k1; x1 += ks2 + 1u;
  TFR(17) TFR(29) TFR(16) TFR(24)
  x0 += ks2; x1 += k0 + 2u;
  TFR(13) TFR(15) TFR(26) TFR(6)
  x0 += k0; x1 += k1 + 3u;
  TFR(17) TFR(29) TFR(16) TFR(24)
  x0 += k1; x1 += ks2 + 4u;
  TFR(13) TFR(15) TFR(26) TFR(6)
  x0 += ks2; x1 += k0 + 5u;
#undef TFR
  o0 = x0; o1 = x1;
}

__device__ __forceinline__ u32 rbits32(u32 kx, u32 ky, u32 i) {
  u32 o0, o1;
  tf2x32(kx, ky, 0u, i, o0, o1);
  return o0 ^ o1;   // partitionable fold
}
// Stable-lexsort-equivalent composite key
#define SELKEY(e) ((((u64)(rbits32(k1x, k1y, (u32)(e)) >> 9)) << 32) | (u32)(e))
#define CSWAP(x, y) { u64 lo_ = x < y ? x : y; u64 hi_ = x < y ? y : x; x = lo_; y = hi_; }

// ---- bf16 helpers (RNE, matches np/jax bf16 cast) ----
__device__ __forceinline__ float q16(float f) {
  u32 x = __builtin_bit_cast(u32, f);
  u32 lsb = (x >> 16) & 1u;
  x = (x + 0x7fffu + lsb) & 0xffff0000u;
  return __builtin_bit_cast(float, x);
}
__device__ __forceinline__ u16 rne16(float f) {
  u32 x = __builtin_bit_cast(u32, f);
  u32 lsb = (x >> 16) & 1u;
  return (u16)((x + 0x7fffu + lsb) >> 16);
}
__device__ __forceinline__ float bfbits2f(u16 b) {
  u32 x = ((u32)b) << 16;
  return __builtin_bit_cast(float, x);
}

// ---- Phase 1: degree histogram, 4-way sharded counters ----
__global__ __launch_bounds__(256) void k_hist(const int4* __restrict__ dkg4,
                                              int* __restrict__ degs) {
  int i = blockIdx.x * 256 + threadIdx.x;
  if (i >= NE / 4) return;
  int4 A = dkg4[3 * i], B = dkg4[3 * i + 1], C = dkg4[3 * i + 2];
  int s = (threadIdx.x & 3) * SH;
  atomicAdd(&degs[s + A.x], 1);
  atomicAdd(&degs[s + A.w], 1);
  atomicAdd(&degs[s + B.z], 1);
  atomicAdd(&degs[s + C.y], 1);
}

// ---- Phase 2: merge deg shards; per-drug candidate threshold; init cnt/nflag.
// thr guarantees: deg<=40 -> pass-all (exact, covers deg<16 extras);
// else mean ~48 candidates. cnt>=16 => candidates contain the exact top-16.
__global__ __launch_bounds__(256) void k_thr(const int* __restrict__ degs,
                                             int* __restrict__ deg,
                                             u32* __restrict__ thr,
                                             int* __restrict__ cnt,
                                             int* __restrict__ nflag) {
  int d = blockIdx.x * 256 + threadIdx.x;
  if (d == 0) *nflag = 0;
  if (d >= NDRUGS) return;
  int dg = degs[d] + degs[SH + d] + degs[2 * SH + d] + degs[3 * SH + d];
  deg[d] = dg;
  cnt[d] = 0;
  thr[d] = (dg <= 40) ? 0x800000u
                      : (402653184u + (u32)dg - 1u) / (u32)dg;  // ceil(48*2^23/dg)
}

// ---- Phase 3: candidate emission, SINGLE PASS (thr staged in 40 KB LDS) ----
__global__ __launch_bounds__(256) void k_cand(const int4* __restrict__ dkg4,
                                              const u32* __restrict__ thr,
                                              int* __restrict__ cnt,
                                              int* __restrict__ cand,
                                              int* __restrict__ nflag,
                                              int* __restrict__ flaglist,
                                              u32 k1x, u32 k1y) {
  __shared__ u32 thr_l[NDRUGS];               // 40 KB -> 4 blocks/CU
  for (int j = threadIdx.x; j < NDRUGS; j += 256) thr_l[j] = thr[j];
  __syncthreads();
  int i = blockIdx.x * 256 + threadIdx.x;
  if (i >= NE / 4) return;
  int4 A = dkg4[3 * i], B = dkg4[3 * i + 1], C = dkg4[3 * i + 2];
  int h[4] = {A.x, A.w, B.z, C.y};
  int e0 = 4 * i;
#pragma unroll
  for (int k = 0; k < 4; k++) {
    u32 rb = rbits32(k1x, k1y, (u32)(e0 + k));
    if ((rb >> 9) < thr_l[h[k]]) {
      int pos = atomicAdd(&cnt[h[k]], 1);
      if (pos < CSLOT) cand[h[k] * CSLOT + pos] = e0 + k;
      else if (pos == CSLOT) {
        int ix = atomicAdd(nflag, 1);
        if (ix < 256) flaglist[ix] = h[k];
      }
    }
  }
}

// ---- Phase 4: wave-per-drug top-16 from candidates ----
__global__ __launch_bounds__(256) void k_select(const int* __restrict__ cand,
                                                const int* __restrict__ cnt,
                                                const int* __restrict__ deg,
                                                int* __restrict__ sel,
                                                int* __restrict__ nflag,
                                                int* __restrict__ flaglist,
                                                u32 k1x, u32 k1y,
                                                u32 khx, u32 khy,
                                                u32 klx, u32 kly) {
  __shared__ int asel[4][16];
  int tid = threadIdx.x, lane = tid & 63, wv = tid >> 6;
  int d = blockIdx.x * 4 + wv;
  if (d >= NDRUGS) return;
  int dg = deg[d], n = cnt[d], off = d * CSLOT;
  if (dg <= 0) {
    if (lane < 16) sel[d * SSIZE + lane] = -1;
    return;
  }
  if (dg >= SSIZE) {
    if (n < SSIZE || n > CSLOT) {          // filter failed -> exact fallback
      if (lane == 0) {
        int ix = atomicAdd(nflag, 1);
        if (ix < 256) flaglist[ix] = d;
      }
      return;
    }
    u64 a0 = U64MAX, a1 = U64MAX;
    if (lane < n)      a0 = SELKEY(cand[off + lane]);
    if (lane + 64 < n) a1 = SELKEY(cand[off + lane + 64]);
    CSWAP(a0, a1)
    int h = 0; u32 my = 0;
#pragma unroll
    for (int r = 0; r < SSIZE; r++) {
      u64 ex = (h == 0) ? a0 : (h == 1) ? a1 : U64MAX;
      u64 g = ex;
#pragma unroll
      for (int m = 1; m < 64; m <<= 1) {
        u64 o = __shfl_xor(g, m, 64);
        g = o < g ? o : g;
      }
      if (lane == r) my = (u32)g;
      if (ex == g) h++;
    }
    if (lane < 16) sel[d * SSIZE + lane] = (int)my;
  } else {
    // deg<16: thr passed all -> n == dg; ascending extraction + extras
    u64 a0 = (lane < n) ? SELKEY(cand[off + lane]) : U64MAX;
    int h = 0;
    for (int r = 0; r < n; r++) {
      u64 ex = (h == 0) ? a0 : U64MAX;
      u64 g = ex;
#pragma unroll
      for (int m = 1; m < 64; m <<= 1) {
        u64 o = __shfl_xor(g, m, 64);
        g = o < g ? o : g;
      }
      if (lane == 0) asel[wv][r] = (int)(u32)g;
      if (ex == g) h++;
    }
    if (lane < n) sel[d * SSIZE + lane] = asel[wv][lane];
    int need = SSIZE - n;
    const u32 span = 0x7fffffffu;           // 2^31-1; 2^32 % span = 2
    if (lane < need) {
      u32 j = (u32)(d * SSIZE + lane);
      u32 hi = rbits32(khx, khy, j) % span;
      u32 lo = rbits32(klx, kly, j) % span;
      u32 u = (hi * 2u + lo) % span;        // uint32 wraparound: JAX-exact
      int idx = (int)(u % (u32)n);
      sel[d * SSIZE + n + lane] = asel[wv][idx];
    }
  }
}

// ---- Phase 4b: exact fallback for flagged drugs (normally: load, exit) ----
__global__ __launch_bounds__(256) void k_fix(const int* __restrict__ dkg,
                                             const int* __restrict__ nflag,
                                             const int* __restrict__ flaglist,
                                             int* __restrict__ sel,
                                             u32 k1x, u32 k1y) {
  int nf = *nflag;
  if (nf <= 0) return;
  if (nf > 256) nf = 256;
  __shared__ u64 pool[256 * 16];
  int tid = threadIdx.x;
  for (int f = 0; f < nf; f++) {
    int d = flaglist[f];
    u64 loc[16];
#pragma unroll
    for (int i = 0; i < 16; i++) loc[i] = U64MAX;
    u64 mx = U64MAX; int mi = 0;
    for (int e = tid; e < NE; e += 256) {
      if (dkg[3 * e] == d) {
        u64 k = SELKEY(e);
        if (k < mx) {
          loc[mi] = k; mx = 0;
          for (int i = 0; i < 16; i++)
            if (loc[i] > mx) { mx = loc[i]; mi = i; }
        }
      }
    }
#pragma unroll
    for (int i = 0; i < 16; i++) pool[tid * 16 + i] = loc[i];
    __syncthreads();
    if (tid == 0) {
      u64 best[16];
#pragma unroll
      for (int i = 0; i < 16; i++) best[i] = U64MAX;
      u64 bm = U64MAX; int bi = 0;
      for (int i = 0; i < 256 * 16; i++) {
        u64 k = pool[i];
        if (k < bm) {
          best[bi] = k; bm = 0;
          for (int j = 0; j < 16; j++)
            if (best[j] > bm) { bm = best[j]; bi = j; }
        }
      }
      for (int s = 0; s < 16; s++) sel[d * SSIZE + s] = (int)(u32)best[s];
    }
    __syncthreads();
  }
}

// ---- Phase 5: edge-MLP + neighbor gather via MFMA (4 drugs/wave) ----
__global__ __launch_bounds__(256, 2) void k_gather(const int* __restrict__ sel,
                                                   const int* __restrict__ dkg,
                                                   const float* __restrict__ drug,
                                                   const float* __restrict__ rel,
                                                   const float* __restrict__ tail,
                                                   const float* __restrict__ W1,
                                                   const float* __restrict__ b1,
                                                   const float* __restrict__ W2,
                                                   const float* __restrict__ b2,
                                                   float* __restrict__ neigh,
                                                   float* __restrict__ psq) {
  __shared__ __align__(16) u16 Vh[4][16][72];
  __shared__ __align__(16) u16 Vl[4][16][72];
  __shared__ float rsp[4][64];
  int tid = threadIdx.x, lane = tid & 63, wv = tid >> 6;
  int quad = lane >> 4, c = lane & 15;

  if (blockIdx.x == 0 && tid < 128) psq[tid] = 0.f;   // init stats accumulators
  {                                             // W2 row-sums, 256-thread split
    int r_ = tid & 63, ks = tid >> 6;
    float s = 0.f;
    for (int k = ks * 16; k < ks * 16 + 16; k++) s += q16(W2[r_ * 64 + k]);
    rsp[ks][r_] = s;
  }
  __syncthreads();

  bf16x8 bw[4][2];
#pragma unroll
  for (int t = 0; t < 4; t++)
#pragma unroll
    for (int s = 0; s < 2; s++) {
      union { short h[8]; bf16x8 v; } u;
#pragma unroll
      for (int jj = 0; jj < 8; jj++)
        u.h[jj] = (short)rne16(W1[(s * 32 + quad * 8 + jj) * 64 + t * 16 + c]);
      bw[t][s] = u.v;
    }
  float b1t[4], w2t[4];
#pragma unroll
  for (int t = 0; t < 4; t++) {
    b1t[t] = q16(b1[t * 16 + c]);
    int rr = t * 16 + c;
    w2t[t] = rsp[0][rr] + rsp[1][rr] + rsp[2][rr] + rsp[3][rr];
  }
  float sb2 = q16(b2[lane]);
#pragma unroll
  for (int m = 32; m; m >>= 1) sb2 += __shfl_xor(sb2, m, 64);

  int d0 = (blockIdx.x * 4 + wv) * 4;           // 4 drugs per wave, grid 625
  int sv = sel[d0 * SSIZE + lane];              // 64 slots = 4 drugs x 16
  int es = sv < 0 ? 0 : sv;
  int rlv = dkg[3 * es + 2];
  int tlv = dkg[3 * es + 1];

#pragma unroll 1
  for (int dd = 0; dd < 4; dd++) {
    int d = d0 + dd;
    float dr = q16(drug[d * 64 + lane]);
#pragma unroll
    for (int e = 0; e < 16; e++) {
      int rl = __shfl(rlv, dd * 16 + e, 64);
      float v = dr * q16(rel[rl * 64 + lane]);
      u16 hb = rne16(v);
      float lo = v - bfbits2f(hb);
      Vh[wv][e][lane] = hb;
      Vl[wv][e][lane] = rne16(lo);          // exact split
    }
    bf16x8 ah[2], al[2];
#pragma unroll
    for (int s = 0; s < 2; s++) {
      ah[s] = *(const bf16x8*)&Vh[wv][c][s * 32 + quad * 8];
      al[s] = *(const bf16x8*)&Vl[wv][c][s * 32 + quad * 8];
    }
    f32x4 acc[4];
#pragma unroll
    for (int t = 0; t < 4; t++) {
      acc[t] = (f32x4){b1t[t], b1t[t], b1t[t], b1t[t]};
#pragma unroll
      for (int s = 0; s < 2; s++) {
        acc[t] = __builtin_amdgcn_mfma_f32_16x16x32_bf16(ah[s], bw[t][s], acc[t], 0, 0, 0);
        acc[t] = __builtin_amdgcn_mfma_f32_16x16x32_bf16(al[s], bw[t][s], acc[t], 0, 0, 0);
      }
    }
    float p[4] = {0.f, 0.f, 0.f, 0.f};
#pragma unroll
    for (int t = 0; t < 4; t++)
#pragma unroll
      for (int r = 0; r < 4; r++)
        p[r] = fmaf(1.f / (1.f + __expf(-acc[t][r])), w2t[t], p[r]);
#pragma unroll
    for (int m = 1; m < 16; m <<= 1) {
#pragma unroll
      for (int r = 0; r < 4; r++) p[r] += __shfl_xor(p[r], m, 64);
    }
#pragma unroll
    for (int r = 0; r < 4; r++) p[r] += sb2;
    float a0 = 0.f, a1 = 0.f, a2 = 0.f, a3 = 0.f;
#pragma unroll
    for (int e = 0; e < 16; e += 4) {
#pragma unroll
      for (int k = 0; k < 4; k++) {
        int sl = dd * 16 + e + k;
        int ee = __shfl(sv, sl, 64);
        int tl = __shfl(tlv, sl, 64);
        float sc = __shfl(p[(e + k) & 3], ((e + k) >> 2) << 4, 64);
        float tv = q16(tail[tl * 64 + lane]);
        if (ee >= 0) {
          if (k == 0) a0 = fmaf(sc, tv, a0);
          else if (k == 1) a1 = fmaf(sc, tv, a1);
          else if (k == 2) a2 = fmaf(sc, tv, a2);
          else a3 = fmaf(sc, tv, a3);
        }
      }
    }
    neigh[d * 64 + lane] = (a0 + a1) + (a2 + a3);
  }
}

// ---- Phase 5b: y = [drug | neigh] @ Wc + bc via MFMA + fused BN stats ----
__global__ __launch_bounds__(256, 2) void k_epi(const float* __restrict__ drug,
                                                const float* __restrict__ neigh,
                                                const float* __restrict__ Wc,
                                                const float* __restrict__ bc,
                                                float* __restrict__ y,
                                                float* __restrict__ ps,
                                                float* __restrict__ pq) {
  __shared__ __align__(16) u16 Ah[4][16][136];
  __shared__ __align__(16) u16 Al[4][16][72];
  __shared__ float Sp[16][64], Qp[16][64];
  int tid = threadIdx.x, lane = tid & 63, wv = tid >> 6;
  int quad = lane >> 4, c = lane & 15;

  bf16x8 bw[4][4];
#pragma unroll
  for (int t = 0; t < 4; t++)
#pragma unroll
    for (int s = 0; s < 4; s++) {
      union { short h[8]; bf16x8 v; } u;
#pragma unroll
      for (int jj = 0; jj < 8; jj++)
        u.h[jj] = (short)rne16(Wc[(s * 32 + quad * 8 + jj) * 64 + t * 16 + c]);
      bw[t][s] = u.v;
    }
  float bct[4];
#pragma unroll
  for (int t = 0; t < 4; t++) bct[t] = q16(bc[t * 16 + c]);

  int D0 = (blockIdx.x * 4 + wv) * 16;
#pragma unroll 1
  for (int rr = 0; rr < 16; rr++) {
    int d = D0 + rr;
    int dsafe = d < NDRUGS ? d : NDRUGS - 1;
    float dv = q16(drug[dsafe * 64 + lane]);
    Ah[wv][rr][lane] = rne16(dv);
    float nv = neigh[dsafe * 64 + lane];
    u16 nh = rne16(nv);
    Ah[wv][rr][64 + lane] = nh;
    Al[wv][rr][lane] = rne16(nv - bfbits2f(nh));
  }
  f32x4 acc[4];
#pragma unroll
  for (int t = 0; t < 4; t++) acc[t] = (f32x4){bct[t], bct[t], bct[t], bct[t]};
#pragma unroll
  for (int s = 0; s < 4; s++) {
    bf16x8 a = *(const bf16x8*)&Ah[wv][c][s * 32 + quad * 8];
#pragma unroll
    for (int t = 0; t < 4; t++)
      acc[t] = __builtin_amdgcn_mfma_f32_16x16x32_bf16(a, bw[t][s], acc[t], 0, 0, 0);
  }
#pragma unroll
  for (int s = 0; s < 2; s++) {
    bf16x8 a = *(const bf16x8*)&Al[wv][c][s * 32 + quad * 8];
#pragma unroll
    for (int t = 0; t < 4; t++)
      acc[t] = __builtin_amdgcn_mfma_f32_16x16x32_bf16(a, bw[t][2 + s], acc[t], 0, 0, 0);
  }
  // write y + per-lane column partials for BN stats
#pragma unroll
  for (int t = 0; t < 4; t++) {
    float s = 0.f, q = 0.f;
#pragma unroll
    for (int r = 0; r < 4; r++) {
      int row = D0 + quad * 4 + r;
      if (row < NDRUGS) {
        float v = acc[t][r];
        y[row * 64 + t * 16 + c] = v;
        s += v;
        q = fmaf(v, v, q);
      }
    }
    Sp[wv * 4 + quad][t * 16 + c] = s;
    Qp[wv * 4 + quad][t * 16 + c] = q;
  }
  __syncthreads();
  if (tid < 64) {
    float s = 0.f, q = 0.f;
#pragma unroll
    for (int p = 0; p < 16; p++) { s += Sp[p][tid]; q += Qp[p][tid]; }
    atomicAdd(&ps[tid], s);
    atomicAdd(&pq[tid], q);
  }
}

// ---- Phase 7: BN (stats inline) + passthrough copies, float4 ----
__global__ __launch_bounds__(256) void k_final(const float4* __restrict__ HFE4,
                                               const float4* __restrict__ Xv4,
                                               const float* __restrict__ gamma,
                                               const float* __restrict__ beta,
                                               const float* __restrict__ ps,
                                               const float* __restrict__ pq,
                                               float4* __restrict__ out4) {
  int i4 = blockIdx.x * 256 + threadIdx.x;
  if (i4 < 160000) {
    float4 a = HFE4[i4];
    a.x = q16(a.x); a.y = q16(a.y); a.z = q16(a.z); a.w = q16(a.w);
    out4[i4] = a;
  } else if (i4 < 320000) {
    int idx4 = i4 - 160000;
    int j0 = (idx4 * 4) & 63;
    float4 S = *(const float4*)&ps[j0];
    float4 Q = *(const float4*)&pq[j0];
    float4 v = out4[i4];                      // y, in place
    float4 r;
#define BN1(X, SS, QQ, JJ)                                                 \
    { float m = SS / 10000.f;                                              \
      float inv = rsqrtf(QQ / 10000.f - m * m + 1e-5f);                    \
      r.X = q16(fmaf(q16(gamma[JJ]) * (v.X - m), inv, q16(beta[JJ]))); }
    BN1(x, S.x, Q.x, j0 + 0)
    BN1(y, S.y, Q.y, j0 + 1)
    BN1(z, S.z, Q.z, j0 + 2)
    BN1(w, S.w, Q.w, j0 + 3)
#undef BN1
    out4[i4] = r;
  } else if (i4 < 322500) {
    float4 a = Xv4[i4 - 320000];
    a.x = q16(a.x); a.y = q16(a.y); a.z = q16(a.z); a.w = q16(a.w);
    out4[i4] = a;
  }
}

extern "C" void kernel_launch(void* const* d_in, const int* in_sizes, int n_in,
                              void* d_out, int out_size, void* d_ws, size_t ws_size,
                              hipStream_t stream) {
  const float* drug = (const float*)d_in[2];
  const float* rel  = (const float*)d_in[3];
  const float* tail = (const float*)d_in[4];
  const float* W1   = (const float*)d_in[5];
  const float* b1   = (const float*)d_in[6];
  const float* W2   = (const float*)d_in[7];
  const float* b2   = (const float*)d_in[8];
  const float* Wc   = (const float*)d_in[9];
  const float* bc   = (const float*)d_in[10];
  const float* gam  = (const float*)d_in[11];
  const float* bet  = (const float*)d_in[12];
  const int*   dkg  = (const int*)d_in[13];
  float* out = (float*)d_out;
  float* y = out + 640000;                   // Output-1 region doubles as y

  // ---- Workspace (footprint 4,760,004 B <= proven-safe 4,760,512) ----
  char* w = (char*)d_ws;
  int*   cand   = (int*)(w);                 // 10000*96*4 = 3,840,000; dead after k_fix
  float* neigh  = (float*)(w);               // 2.56 MB, overlays dead cand
  float* ps     = (float*)(w + 2600000);     // 256 B (inside dead cand region)
  float* pq     = (float*)(w + 2600256);     // 256 B
  int*   flagl  = (int*)(w + 3900000);       // 1 KB
  int*   nflag  = (int*)(w + 3904096);       // 4 B
  int*   degs   = (int*)(w + 4000000);       // 4 x SH shards; dead after k_thr
  int*   sel    = (int*)(w + 4000000);       // 640 KB, overlays degs (post-thr)
  int*   cnt    = (int*)(w + 4640000);       // 40 KB
  u32*   thr    = (u32*)(w + 4680000);       // 40 KB
  int*   deg    = (int*)(w + 4720000);       // 40 KB

  // Threefry key derivation (seed 42, partitionable split semantics)
  u32 k1x, k1y, k2x, k2y, khx, khy, klx, kly;
  tf2x32(0u, 42u, 0u, 0u, k1x, k1y);   // split(key)[0] -> uniform r
  tf2x32(0u, 42u, 0u, 1u, k2x, k2y);   // split(key)[1] -> randint key
  tf2x32(k2x, k2y, 0u, 0u, khx, khy);  // split(k2)[0] -> higher_bits
  tf2x32(k2x, k2y, 0u, 1u, klx, kly);  // split(k2)[1] -> lower_bits

  hipMemsetAsync(degs, 0, 4 * SH * sizeof(int), stream);
  k_hist<<<(NE / 4 + 255) / 256, 256, 0, stream>>>((const int4*)dkg, degs);
  k_thr<<<40, 256, 0, stream>>>(degs, deg, thr, cnt, nflag);
  k_cand<<<(NE / 4 + 255) / 256, 256, 0, stream>>>((const int4*)dkg, thr, cnt,
                                                   cand, nflag, flagl, k1x, k1y);
  k_select<<<2500, 256, 0, stream>>>(cand, cnt, deg, sel, nflag, flagl,
                                     k1x, k1y, khx, khy, klx, kly);
  k_fix<<<1, 256, 0, stream>>>(dkg, nflag, flagl, sel, k1x, k1y);
  k_gather<<<625, 256, 0, stream>>>(sel, dkg, drug, rel, tail,
                                    W1, b1, W2, b2, neigh, ps);
  k_epi<<<157, 256, 0, stream>>>(drug, neigh, Wc, bc, y, ps, pq);
  k_final<<<(322500 + 255) / 256, 256, 0, stream>>>((const float4*)d_in[0],
                                                    (const float4*)d_in[1],
                                                    gam, bet, ps, pq,
                                                    (float4*)out);
}